// Round 1
// baseline (3268.814 us; speedup 1.0000x reference)
//
#include <hip/hip_runtime.h>
#include <stdint.h>

#define N_TOK 4096
#define DIM_IN 512
#define NH 12
#define HD 64
#define CDIM 768   // NH*HD

using f32x4  = __attribute__((ext_vector_type(4))) float;
using bf16x8 = __attribute__((ext_vector_type(8))) short;

static __device__ __forceinline__ unsigned short f2bf(float f){
    union { float f; unsigned int u; } v; v.f = f;
    unsigned int r = v.u + 0x7fffu + ((v.u >> 16) & 1u);
    return (unsigned short)(r >> 16);
}

// ---------------------------------------------------------------------------
// proj: out[n][c] = (sum_d g[n][d]*W[c][d] + B[c]) * (scale ? scale[c/64] : 1)
// stored as bf16.  64x64 tile, BK=16, 256 threads, 4x4 micro.
// ---------------------------------------------------------------------------
__global__ __launch_bounds__(256) void proj_kernel(
    const float* __restrict__ g, const float* __restrict__ W,
    const float* __restrict__ B, const float* __restrict__ scale,
    unsigned short* __restrict__ out)
{
    __shared__ float at[16][68];
    __shared__ float bt[16][68];
    const int n0 = blockIdx.x * 64, c0 = blockIdx.y * 64;
    const int t  = threadIdx.x;
    const int tx = t & 15, ty = t >> 4;
    const int lr = t >> 2, lk = (t & 3) * 4;
    float acc[4][4] = {};
    for (int d0 = 0; d0 < DIM_IN; d0 += 16){
        __syncthreads();
        f32x4 gv = *(const f32x4*)&g[(size_t)(n0 + lr) * DIM_IN + d0 + lk];
        at[lk+0][lr] = gv[0]; at[lk+1][lr] = gv[1]; at[lk+2][lr] = gv[2]; at[lk+3][lr] = gv[3];
        f32x4 wv = *(const f32x4*)&W[(size_t)(c0 + lr) * DIM_IN + d0 + lk];
        bt[lk+0][lr] = wv[0]; bt[lk+1][lr] = wv[1]; bt[lk+2][lr] = wv[2]; bt[lk+3][lr] = wv[3];
        __syncthreads();
        #pragma unroll
        for (int kk = 0; kk < 16; kk++){
            f32x4 av = *(const f32x4*)&at[kk][ty*4];
            f32x4 bv = *(const f32x4*)&bt[kk][tx*4];
            #pragma unroll
            for (int i = 0; i < 4; i++)
                #pragma unroll
                for (int j = 0; j < 4; j++)
                    acc[i][j] += av[i] * bv[j];
        }
    }
    #pragma unroll
    for (int i = 0; i < 4; i++){
        const int n = n0 + ty*4 + i;
        #pragma unroll
        for (int j = 0; j < 4; j++){
            const int c = c0 + tx*4 + j;
            float v = acc[i][j] + B[c];
            if (scale) v *= scale[c >> 6];
            out[(size_t)n * CDIM + c] = f2bf(v);
        }
    }
}

// ---------------------------------------------------------------------------
// forward: per 16x16 (q,k) MFMA tile, 12 head scores -> Hw mix -> adj mask ->
// accumulate sum(exp) per (q-row, h').  atomicAdd partials into l_ws.
// ---------------------------------------------------------------------------
#define TKF 32
#define KBS 776   // ushort stride: 1552 B (16B aligned, 2-way-bank only)

__global__ __launch_bounds__(256, 2) void fwd_kernel(
    const unsigned short* __restrict__ Qb, const unsigned short* __restrict__ Kh,
    const float* __restrict__ adj, const float* __restrict__ HwG,
    float* __restrict__ l_ws, int seg_len)
{
    __shared__ unsigned short kbuf[TKF][KBS];
    __shared__ float hw[NH][12];
    const int t = threadIdx.x;
    if (t < NH * 12) hw[t / 12][t % 12] = HwG[t];
    const int lane = t & 63, wave = t >> 6;
    const int quad = lane >> 4, col = lane & 15;
    const int qt0 = blockIdx.x * 64 + wave * 16;
    const int kstart = blockIdx.y * seg_len;

    bf16x8 af[NH][2];
    {
        const int arow = qt0 + col;
        #pragma unroll
        for (int h = 0; h < NH; h++)
            #pragma unroll
            for (int kk = 0; kk < 2; kk++)
                af[h][kk] = *(const bf16x8*)&Qb[(size_t)arow * CDIM + h*HD + kk*32 + quad*8];
    }
    f32x4 l4[4][3];
    #pragma unroll
    for (int r = 0; r < 4; r++)
        #pragma unroll
        for (int j = 0; j < 3; j++)
            l4[r][j] = (f32x4){0.f,0.f,0.f,0.f};

    for (int kc = kstart; kc < kstart + seg_len; kc += TKF){
        __syncthreads();
        #pragma unroll
        for (int i = 0; i < 12; i++){
            const int idx = t + 256 * i;
            const int row = idx / 96, cc = (idx % 96) * 8;
            *(bf16x8*)&kbuf[row][cc] = *(const bf16x8*)&Kh[(size_t)(kc + row) * CDIM + cc];
        }
        __syncthreads();
        #pragma unroll
        for (int sub = 0; sub < 2; sub++){
            const int k0 = kc + sub * 16;
            f32x4 tv[4][3];
            #pragma unroll
            for (int r = 0; r < 4; r++)
                #pragma unroll
                for (int j = 0; j < 3; j++)
                    tv[r][j] = (f32x4){0.f,0.f,0.f,0.f};
            #pragma unroll
            for (int h = 0; h < NH; h++){
                bf16x8 b0 = *(const bf16x8*)&kbuf[sub*16 + col][h*HD + quad*8];
                bf16x8 b1 = *(const bf16x8*)&kbuf[sub*16 + col][h*HD + 32 + quad*8];
                f32x4 s = {0.f,0.f,0.f,0.f};
                s = __builtin_amdgcn_mfma_f32_16x16x32_bf16(af[h][0], b0, s, 0, 0, 0);
                s = __builtin_amdgcn_mfma_f32_16x16x32_bf16(af[h][1], b1, s, 0, 0, 0);
                f32x4 w0 = *(const f32x4*)&hw[h][0];
                f32x4 w1 = *(const f32x4*)&hw[h][4];
                f32x4 w2 = *(const f32x4*)&hw[h][8];
                #pragma unroll
                for (int r = 0; r < 4; r++){
                    tv[r][0] += s[r] * w0;
                    tv[r][1] += s[r] * w1;
                    tv[r][2] += s[r] * w2;
                }
            }
            #pragma unroll
            for (int r = 0; r < 4; r++){
                const float adjv = adj[(size_t)(qt0 + quad*4 + r) * N_TOK + k0 + col];
                #pragma unroll
                for (int j = 0; j < 3; j++){
                    #pragma unroll
                    for (int c = 0; c < 4; c++){
                        const float mm = tv[r][j][c] * adjv;   // matches T*adj
                        if (mm != 0.f) l4[r][j][c] += __expf(mm);
                    }
                }
            }
        }
    }
    #pragma unroll
    for (int r = 0; r < 4; r++)
        #pragma unroll
        for (int j = 0; j < 3; j++)
            #pragma unroll
            for (int c = 0; c < 4; c++){
                float v = l4[r][j][c];
                v += __shfl_xor(v, 1, 16);
                v += __shfl_xor(v, 2, 16);
                v += __shfl_xor(v, 4, 16);
                v += __shfl_xor(v, 8, 16);
                if (col == j*4 + c)
                    atomicAdd(&l_ws[(size_t)(qt0 + quad*4 + r) * NH + (j*4 + c)], v);
            }
}

// ---------------------------------------------------------------------------
// lse + energy
// ---------------------------------------------------------------------------
__global__ __launch_bounds__(256) void lse_energy_kernel(
    const float* __restrict__ l_ws, float* __restrict__ lse_ws,
    const float* __restrict__ betas, float* __restrict__ energy)
{
    const int t = threadIdx.x;
    const int i = blockIdx.x * 256 + t;
    const float l = l_ws[i];
    float lse, ep;
    if (l > 0.f){ lse = logf(l); ep = -(1.f / betas[i % NH]) * lse; }
    else        { lse = -1e30f; ep = 0.f; }
    lse_ws[i] = lse;
    __shared__ float red[256];
    red[t] = ep;
    __syncthreads();
    for (int s = 128; s > 0; s >>= 1){
        if (t < s) red[t] += red[t + s];
        __syncthreads();
    }
    if (t == 0) atomicAdd(energy, red[0]);
}

// ---------------------------------------------------------------------------
// backward: 512 threads / 8 waves per block, 32-row tile, 64-col chunks.
//  - One resident block = 8 waves = 2 waves/SIMD (vs 1 before): latency hiding.
//  - LDS total 160,832 B <= 163,840 (single-workgroup budget).
//  - colbuf XOR-swizzled (c ^= ((t>>3)&3)<<3): phase-B per-element gather goes
//    4-way conflict -> 2-way (free); phase-A b128 reads stay at b128 minimum.
//  - dsbuf stride 72 -> 64 ushorts + swizzle (t ^= (m&7)<<3): saves 6 KB,
//    phase-B a-reads conflict-free.
// Wave mapping: rsub = wave>>2 picks 16-row half, csub = wave&3 picks the
// 16-col subtile (phase A) / head subset h = csub + 4*hh (phase B).
// ---------------------------------------------------------------------------
#define CBS 776   // colbuf ushort stride

__global__ __launch_bounds__(512, 2) void bwd_kernel(
    const unsigned short* __restrict__ rowmat, const unsigned short* __restrict__ colmat,
    const float* __restrict__ adj, const float* __restrict__ HwG,
    const float* __restrict__ lse_ws, const float* __restrict__ betas,
    float* __restrict__ out_part, int seg_len, int mode)
{
    __shared__ unsigned short colbuf[64][CBS];     // 99328 B
    __shared__ unsigned short dsbuf[NH][32][64];   // 49152 B
    __shared__ float adjbuf[32][68];               //  8704 B
    __shared__ float lsebuf[64 * NH];              //  3072 B
    __shared__ float hw[NH][12];                   //   576 B
    const int t = threadIdx.x;
    if (t < NH * 12) hw[t / 12][t % 12] = HwG[t];
    const int lane = t & 63, wave = t >> 6;
    const int quad = lane >> 4, col = lane & 15;
    const int rsub = wave >> 2, csub = wave & 3;
    const int n0 = csub * 16;
    const int rt0 = blockIdx.x * 32;
    const int rbase = rt0 + rsub * 16;       // this wave's 16 rows
    const int cstart = blockIdx.y * seg_len;

    f32x4 invb[3];
    #pragma unroll
    for (int j = 0; j < 3; j++)
        #pragma unroll
        for (int c = 0; c < 4; c++) invb[j][c] = 1.f / betas[j*4 + c];

    bf16x8 af[NH][2];
    {
        const int arow = rbase + col;
        #pragma unroll
        for (int h = 0; h < NH; h++)
            #pragma unroll
            for (int kk = 0; kk < 2; kk++)
                af[h][kk] = *(const bf16x8*)&rowmat[(size_t)arow * CDIM + h*HD + kk*32 + quad*8];
    }
    f32x4 lrow[4][3];
    if (mode == 0){
        #pragma unroll
        for (int r = 0; r < 4; r++)
            #pragma unroll
            for (int j = 0; j < 3; j++)
                lrow[r][j] = *(const f32x4*)&lse_ws[(size_t)(rbase + quad*4 + r) * NH + j*4];
    }
    f32x4 accB[3][4];
    #pragma unroll
    for (int hh = 0; hh < 3; hh++)
        #pragma unroll
        for (int zt = 0; zt < 4; zt++)
            accB[hh][zt] = (f32x4){0.f,0.f,0.f,0.f};

    for (int cb = cstart; cb < cstart + seg_len; cb += 64){
        __syncthreads();
        #pragma unroll
        for (int i = 0; i < 12; i++){
            const int idx = t + 512 * i;
            const int row = idx / 96, cc = (idx % 96) * 8;
            // swizzled store: logical channel c lives at c ^ ((row>>3 & 3)<<3)
            *(bf16x8*)&colbuf[row][cc ^ (((row >> 3) & 3) << 3)] =
                *(const bf16x8*)&colmat[(size_t)(cb + row) * CDIM + cc];
        }
        if (mode == 0){
            const int m = t >> 4, nc = (t & 15) * 4;
            f32x4 a = *(const f32x4*)&adj[(size_t)(rt0 + m) * N_TOK + cb + nc];
            adjbuf[m][nc+0] = a[0]; adjbuf[m][nc+1] = a[1];
            adjbuf[m][nc+2] = a[2]; adjbuf[m][nc+3] = a[3];
        } else {
            const int qr = t >> 3, kc = (t & 7) * 4;
            f32x4 a = *(const f32x4*)&adj[(size_t)(cb + qr) * N_TOK + rt0 + kc];
            adjbuf[kc+0][qr] = a[0]; adjbuf[kc+1][qr] = a[1];
            adjbuf[kc+2][qr] = a[2]; adjbuf[kc+3][qr] = a[3];
        }
        if (mode == 1 && t < 192)
            *(f32x4*)&lsebuf[t*4] = *(const f32x4*)&lse_ws[(size_t)cb * NH + t*4];
        __syncthreads();

        // ---- phase A: this wave's 16 rows x 16 cols (csub subtile) ----
        {
            const int tA = n0 + col;
            const int swzA = ((tA >> 3) & 3) << 3;
            f32x4 G[4][3];
            #pragma unroll
            for (int r = 0; r < 4; r++)
                #pragma unroll
                for (int j = 0; j < 3; j++)
                    G[r][j] = (f32x4){0.f,0.f,0.f,0.f};
            #pragma unroll
            for (int h = 0; h < NH; h++){
                bf16x8 b0 = *(const bf16x8*)&colbuf[tA][(h*HD + quad*8) ^ swzA];
                bf16x8 b1 = *(const bf16x8*)&colbuf[tA][(h*HD + 32 + quad*8) ^ swzA];
                f32x4 s = {0.f,0.f,0.f,0.f};
                s = __builtin_amdgcn_mfma_f32_16x16x32_bf16(af[h][0], b0, s, 0, 0, 0);
                s = __builtin_amdgcn_mfma_f32_16x16x32_bf16(af[h][1], b1, s, 0, 0, 0);
                f32x4 w0 = *(const f32x4*)&hw[h][0];
                f32x4 w1 = *(const f32x4*)&hw[h][4];
                f32x4 w2 = *(const f32x4*)&hw[h][8];
                #pragma unroll
                for (int r = 0; r < 4; r++){
                    G[r][0] += s[r] * w0;
                    G[r][1] += s[r] * w1;
                    G[r][2] += s[r] * w2;
                }
            }
            // convert t-values -> gradient G = -(1/b')*P
            #pragma unroll
            for (int r = 0; r < 4; r++){
                const float adjv = adjbuf[rsub*16 + quad*4 + r][tA];
                f32x4 lv0, lv1, lv2;
                if (mode == 0){ lv0 = lrow[r][0]; lv1 = lrow[r][1]; lv2 = lrow[r][2]; }
                else {
                    lv0 = *(const f32x4*)&lsebuf[tA * NH + 0];
                    lv1 = *(const f32x4*)&lsebuf[tA * NH + 4];
                    lv2 = *(const f32x4*)&lsebuf[tA * NH + 8];
                }
                f32x4 lv[3] = { lv0, lv1, lv2 };
                #pragma unroll
                for (int j = 0; j < 3; j++)
                    #pragma unroll
                    for (int c = 0; c < 4; c++){
                        const float mm = G[r][j][c] * adjv;
                        const float p  = (mm != 0.f) ? __expf(mm - lv[j][c]) : 0.f;
                        G[r][j][c] = -invb[j][c] * p;
                    }
            }
            // dS = G @ Hw^T, bf16 into dsbuf (swizzled: t' = t ^ ((m&7)<<3))
            #pragma unroll
            for (int h = 0; h < NH; h++){
                f32x4 w0 = *(const f32x4*)&hw[h][0];
                f32x4 w1 = *(const f32x4*)&hw[h][4];
                f32x4 w2 = *(const f32x4*)&hw[h][8];
                #pragma unroll
                for (int r = 0; r < 4; r++){
                    f32x4 pr = G[r][0]*w0 + G[r][1]*w1 + G[r][2]*w2;
                    const float d = pr[0] + pr[1] + pr[2] + pr[3];
                    const int m = rsub*16 + quad*4 + r;
                    dsbuf[h][m][tA ^ ((m & 7) << 3)] = f2bf(d);
                }
            }
        }
        __syncthreads();

        // ---- phase B: dRow[m][z] += sum_kk dS[m][kk] * colmat[kk][z] ----
        #pragma unroll
        for (int hh = 0; hh < 3; hh++){
            const int h = csub + hh*4;
            #pragma unroll
            for (int ks = 0; ks < 2; ks++){
                const int mA = rsub*16 + col;
                bf16x8 a = *(const bf16x8*)&dsbuf[h][mA][(ks*32 + quad*8) ^ ((col & 7) << 3)];
                #pragma unroll
                for (int zt = 0; zt < 4; zt++){
                    const int ch = (h*HD + zt*16 + col) ^ (quad << 3);  // gather swizzle
                    bf16x8 b;
                    #pragma unroll
                    for (int jj = 0; jj < 8; jj++)
                        b[jj] = (short)colbuf[ks*32 + quad*8 + jj][ch];
                    accB[hh][zt] = __builtin_amdgcn_mfma_f32_16x16x32_bf16(a, b, accB[hh][zt], 0, 0, 0);
                }
            }
        }
    }
    float* outp = out_part + (size_t)blockIdx.y * N_TOK * CDIM;
    #pragma unroll
    for (int hh = 0; hh < 3; hh++){
        const int h = csub + hh*4;
        #pragma unroll
        for (int zt = 0; zt < 4; zt++)
            #pragma unroll
            for (int r = 0; r < 4; r++)
                outp[(size_t)(rbase + quad*4 + r) * CDIM + h*HD + zt*16 + col] = accB[hh][zt][r];
    }
}

// ---------------------------------------------------------------------------
// final: dg[n][d] = sum_c beta[c/64]*dQb[n][c]*Wq[c][d] + dKh[n][c]*Wk[c][d]
// ---------------------------------------------------------------------------
__global__ __launch_bounds__(256) void final_dg_kernel(
    const float* __restrict__ dQbp, const float* __restrict__ dKhp,
    const float* __restrict__ Wq, const float* __restrict__ Wk,
    const float* __restrict__ betas, float* __restrict__ dg, int nseg)
{
    __shared__ float at[16][68];
    __shared__ float bt[16][68];
    const int n0 = blockIdx.x * 64, d0 = blockIdx.y * 64;
    const int t  = threadIdx.x;
    const int tx = t & 15, ty = t >> 4;
    const int lr = t >> 2, lk = (t & 3) * 4;
    float acc[4][4] = {};
    for (int src = 0; src < 2; src++){
        const float* P = src ? dKhp : dQbp;
        const float* W = src ? Wk  : Wq;
        for (int c0 = 0; c0 < CDIM; c0 += 16){
            __syncthreads();
            f32x4 a = {0.f,0.f,0.f,0.f};
            for (int s = 0; s < nseg; s++)
                a += *(const f32x4*)&P[((size_t)s * N_TOK + n0 + lr) * CDIM + c0 + lk];
            if (src == 0){
                const float bs = betas[(c0 + lk) >> 6];
                a *= bs;
            }
            at[lk+0][lr] = a[0]; at[lk+1][lr] = a[1]; at[lk+2][lr] = a[2]; at[lk+3][lr] = a[3];
            {
                const int kk = t >> 4, dd = (t & 15) * 4;
                f32x4 wv = *(const f32x4*)&W[(size_t)(c0 + kk) * DIM_IN + d0 + dd];
                bt[kk][dd+0] = wv[0]; bt[kk][dd+1] = wv[1]; bt[kk][dd+2] = wv[2]; bt[kk][dd+3] = wv[3];
            }
            __syncthreads();
            #pragma unroll
            for (int kk = 0; kk < 16; kk++){
                f32x4 av = *(const f32x4*)&at[kk][ty*4];
                f32x4 bv = *(const f32x4*)&bt[kk][tx*4];
                #pragma unroll
                for (int i = 0; i < 4; i++)
                    #pragma unroll
                    for (int j = 0; j < 4; j++)
                        acc[i][j] += av[i] * bv[j];
            }
        }
    }
    #pragma unroll
    for (int i = 0; i < 4; i++)
        #pragma unroll
        for (int j = 0; j < 4; j++)
            dg[(size_t)(n0 + ty*4 + i) * DIM_IN + d0 + tx*4 + j] = acc[i][j];
}

// ---------------------------------------------------------------------------
extern "C" void kernel_launch(void* const* d_in, const int* in_sizes, int n_in,
                              void* d_out, int out_size, void* d_ws, size_t ws_size,
                              hipStream_t stream)
{
    const float* g     = (const float*)d_in[0];
    const float* adj   = (const float*)d_in[1];
    const float* Wk    = (const float*)d_in[2];
    const float* Wq    = (const float*)d_in[3];
    const float* Hw    = (const float*)d_in[4];
    const float* Bk    = (const float*)d_in[5];
    const float* Bq    = (const float*)d_in[6];
    const float* betas = (const float*)d_in[7];
    float* out = (float*)d_out;

    char* ws = (char*)d_ws;
    const size_t szQb   = (size_t)N_TOK * CDIM * sizeof(unsigned short); // 6291456
    const size_t szL    = (size_t)N_TOK * NH * sizeof(float);            // 196608
    const size_t szPart = (size_t)N_TOK * CDIM * sizeof(float);          // 12582912

    unsigned short* Qb = (unsigned short*)(ws);
    unsigned short* Kh = (unsigned short*)(ws + szQb);
    float* l_ws   = (float*)(ws + 2*szQb);
    float* lse_ws = (float*)(ws + 2*szQb + szL);
    char*  parts  = ws + 2*szQb + 2*szL;
    const size_t base = 2*szQb + 2*szL;

    int KS = 1;
    if      (ws_size >= base + 8*szPart) KS = 4;
    else if (ws_size >= base + 4*szPart) KS = 2;
    float* dQbp = (float*)parts;
    float* dKhp = (float*)(parts + (size_t)KS * szPart);

    hipMemsetAsync(l_ws, 0, szL, stream);
    hipMemsetAsync(d_out, 0, sizeof(float), stream);

    proj_kernel<<<dim3(64, 12), 256, 0, stream>>>(g, Wq, Bq, betas, Qb);
    proj_kernel<<<dim3(64, 12), 256, 0, stream>>>(g, Wk, Bk, nullptr, Kh);
    fwd_kernel<<<dim3(64, 8), 256, 0, stream>>>(Qb, Kh, adj, Hw, l_ws, N_TOK / 8);
    lse_energy_kernel<<<dim3(192), 256, 0, stream>>>(l_ws, lse_ws, betas, out);
    bwd_kernel<<<dim3(128, KS), 512, 0, stream>>>(Qb, Kh, adj, Hw, lse_ws, betas,
                                                  dQbp, N_TOK / KS, 0);
    bwd_kernel<<<dim3(128, KS), 512, 0, stream>>>(Kh, Qb, adj, Hw, lse_ws, betas,
                                                  dKhp, N_TOK / KS, 1);
    final_dg_kernel<<<dim3(64, 8), 256, 0, stream>>>(dQbp, dKhp, Wq, Wk, betas,
                                                     out + 1, KS);
}

// Round 2
// 2200.856 us; speedup vs baseline: 1.4852x; 1.4852x over previous
//
#include <hip/hip_runtime.h>
#include <stdint.h>

#define N_TOK 4096
#define DIM_IN 512
#define NH 12
#define HD 64
#define CDIM 768   // NH*HD

using f32x4  = __attribute__((ext_vector_type(4))) float;
using bf16x8 = __attribute__((ext_vector_type(8))) short;

static __device__ __forceinline__ unsigned short f2bf(float f){
    union { float f; unsigned int u; } v; v.f = f;
    unsigned int r = v.u + 0x7fffu + ((v.u >> 16) & 1u);
    return (unsigned short)(r >> 16);
}

// ---------------------------------------------------------------------------
// proj: out[n][c] = (sum_d g[n][d]*W[c][d] + B[c]) * (scale ? scale[c/64] : 1)
// stored as bf16.  64x64 tile, BK=16, 256 threads, 4x4 micro.
// ---------------------------------------------------------------------------
__global__ __launch_bounds__(256) void proj_kernel(
    const float* __restrict__ g, const float* __restrict__ W,
    const float* __restrict__ B, const float* __restrict__ scale,
    unsigned short* __restrict__ out)
{
    __shared__ float at[16][68];
    __shared__ float bt[16][68];
    const int n0 = blockIdx.x * 64, c0 = blockIdx.y * 64;
    const int t  = threadIdx.x;
    const int tx = t & 15, ty = t >> 4;
    const int lr = t >> 2, lk = (t & 3) * 4;
    float acc[4][4] = {};
    for (int d0 = 0; d0 < DIM_IN; d0 += 16){
        __syncthreads();
        f32x4 gv = *(const f32x4*)&g[(size_t)(n0 + lr) * DIM_IN + d0 + lk];
        at[lk+0][lr] = gv[0]; at[lk+1][lr] = gv[1]; at[lk+2][lr] = gv[2]; at[lk+3][lr] = gv[3];
        f32x4 wv = *(const f32x4*)&W[(size_t)(c0 + lr) * DIM_IN + d0 + lk];
        bt[lk+0][lr] = wv[0]; bt[lk+1][lr] = wv[1]; bt[lk+2][lr] = wv[2]; bt[lk+3][lr] = wv[3];
        __syncthreads();
        #pragma unroll
        for (int kk = 0; kk < 16; kk++){
            f32x4 av = *(const f32x4*)&at[kk][ty*4];
            f32x4 bv = *(const f32x4*)&bt[kk][tx*4];
            #pragma unroll
            for (int i = 0; i < 4; i++)
                #pragma unroll
                for (int j = 0; j < 4; j++)
                    acc[i][j] += av[i] * bv[j];
        }
    }
    #pragma unroll
    for (int i = 0; i < 4; i++){
        const int n = n0 + ty*4 + i;
        #pragma unroll
        for (int j = 0; j < 4; j++){
            const int c = c0 + tx*4 + j;
            float v = acc[i][j] + B[c];
            if (scale) v *= scale[c >> 6];
            out[(size_t)n * CDIM + c] = f2bf(v);
        }
    }
}

// ---------------------------------------------------------------------------
// forward: per 16x16 (q,k) MFMA tile, 12 head scores -> Hw mix -> adj mask ->
// accumulate sum(exp) per (q-row, h').  atomicAdd partials into l_ws.
// ---------------------------------------------------------------------------
#define TKF 32
#define KBS 776   // ushort stride: 1552 B (16B aligned, 2-way-bank only)

__global__ __launch_bounds__(256, 2) void fwd_kernel(
    const unsigned short* __restrict__ Qb, const unsigned short* __restrict__ Kh,
    const float* __restrict__ adj, const float* __restrict__ HwG,
    float* __restrict__ l_ws, int seg_len)
{
    __shared__ unsigned short kbuf[TKF][KBS];
    __shared__ float hw[NH][12];
    const int t = threadIdx.x;
    if (t < NH * 12) hw[t / 12][t % 12] = HwG[t];
    const int lane = t & 63, wave = t >> 6;
    const int quad = lane >> 4, col = lane & 15;
    const int qt0 = blockIdx.x * 64 + wave * 16;
    const int kstart = blockIdx.y * seg_len;

    bf16x8 af[NH][2];
    {
        const int arow = qt0 + col;
        #pragma unroll
        for (int h = 0; h < NH; h++)
            #pragma unroll
            for (int kk = 0; kk < 2; kk++)
                af[h][kk] = *(const bf16x8*)&Qb[(size_t)arow * CDIM + h*HD + kk*32 + quad*8];
    }
    f32x4 l4[4][3];
    #pragma unroll
    for (int r = 0; r < 4; r++)
        #pragma unroll
        for (int j = 0; j < 3; j++)
            l4[r][j] = (f32x4){0.f,0.f,0.f,0.f};

    for (int kc = kstart; kc < kstart + seg_len; kc += TKF){
        __syncthreads();
        #pragma unroll
        for (int i = 0; i < 12; i++){
            const int idx = t + 256 * i;
            const int row = idx / 96, cc = (idx % 96) * 8;
            *(bf16x8*)&kbuf[row][cc] = *(const bf16x8*)&Kh[(size_t)(kc + row) * CDIM + cc];
        }
        __syncthreads();
        #pragma unroll
        for (int sub = 0; sub < 2; sub++){
            const int k0 = kc + sub * 16;
            f32x4 tv[4][3];
            #pragma unroll
            for (int r = 0; r < 4; r++)
                #pragma unroll
                for (int j = 0; j < 3; j++)
                    tv[r][j] = (f32x4){0.f,0.f,0.f,0.f};
            #pragma unroll
            for (int h = 0; h < NH; h++){
                bf16x8 b0 = *(const bf16x8*)&kbuf[sub*16 + col][h*HD + quad*8];
                bf16x8 b1 = *(const bf16x8*)&kbuf[sub*16 + col][h*HD + 32 + quad*8];
                f32x4 s = {0.f,0.f,0.f,0.f};
                s = __builtin_amdgcn_mfma_f32_16x16x32_bf16(af[h][0], b0, s, 0, 0, 0);
                s = __builtin_amdgcn_mfma_f32_16x16x32_bf16(af[h][1], b1, s, 0, 0, 0);
                f32x4 w0 = *(const f32x4*)&hw[h][0];
                f32x4 w1 = *(const f32x4*)&hw[h][4];
                f32x4 w2 = *(const f32x4*)&hw[h][8];
                #pragma unroll
                for (int r = 0; r < 4; r++){
                    tv[r][0] += s[r] * w0;
                    tv[r][1] += s[r] * w1;
                    tv[r][2] += s[r] * w2;
                }
            }
            #pragma unroll
            for (int r = 0; r < 4; r++){
                const float adjv = adj[(size_t)(qt0 + quad*4 + r) * N_TOK + k0 + col];
                #pragma unroll
                for (int j = 0; j < 3; j++){
                    #pragma unroll
                    for (int c = 0; c < 4; c++){
                        const float mm = tv[r][j][c] * adjv;   // matches T*adj
                        if (mm != 0.f) l4[r][j][c] += __expf(mm);
                    }
                }
            }
        }
    }
    #pragma unroll
    for (int r = 0; r < 4; r++)
        #pragma unroll
        for (int j = 0; j < 3; j++)
            #pragma unroll
            for (int c = 0; c < 4; c++){
                float v = l4[r][j][c];
                v += __shfl_xor(v, 1, 16);
                v += __shfl_xor(v, 2, 16);
                v += __shfl_xor(v, 4, 16);
                v += __shfl_xor(v, 8, 16);
                if (col == j*4 + c)
                    atomicAdd(&l_ws[(size_t)(qt0 + quad*4 + r) * NH + (j*4 + c)], v);
            }
}

// ---------------------------------------------------------------------------
// lse + energy
// ---------------------------------------------------------------------------
__global__ __launch_bounds__(256) void lse_energy_kernel(
    const float* __restrict__ l_ws, float* __restrict__ lse_ws,
    const float* __restrict__ betas, float* __restrict__ energy)
{
    const int t = threadIdx.x;
    const int i = blockIdx.x * 256 + t;
    const float l = l_ws[i];
    float lse, ep;
    if (l > 0.f){ lse = logf(l); ep = -(1.f / betas[i % NH]) * lse; }
    else        { lse = -1e30f; ep = 0.f; }
    lse_ws[i] = lse;
    __shared__ float red[256];
    red[t] = ep;
    __syncthreads();
    for (int s = 128; s > 0; s >>= 1){
        if (t < s) red[t] += red[t + s];
        __syncthreads();
    }
    if (t == 0) atomicAdd(energy, red[0]);
}

// ---------------------------------------------------------------------------
// backward: 512 threads / 8 waves per block, 32-row tile, 64-col chunks.
//  - __launch_bounds__(512, 1): 1 block/CU (LDS forces that anyway) -> VGPR
//    cap 256.  Round-1's (512,2) capped VGPRs at 128 and spilled ~4 GB of
//    scratch traffic per dispatch (FETCH 164MB -> 2.7GB).  Empirically the
//    2nd arg behaves CUDA-style (min blocks/CU): (256,1)->512cap,
//    (256,2)->256cap, (512,2)->128cap.
//  - template<MODE> so the dead path's registers (lrow in mode1, lsebuf
//    addressing in mode0) don't count against the 256 cap.
//  - LDS total 160,832 B <= 163,840 (single-workgroup budget).
//  - colbuf XOR-swizzled; dsbuf stride 64 + XOR swizzle: phase-B reads ~2-way.
// ---------------------------------------------------------------------------
#define CBS 776   // colbuf ushort stride

template<int MODE>
__global__ __launch_bounds__(512, 1) void bwd_kernel(
    const unsigned short* __restrict__ rowmat, const unsigned short* __restrict__ colmat,
    const float* __restrict__ adj, const float* __restrict__ HwG,
    const float* __restrict__ lse_ws, const float* __restrict__ betas,
    float* __restrict__ out_part, int seg_len)
{
    __shared__ unsigned short colbuf[64][CBS];     // 99328 B
    __shared__ unsigned short dsbuf[NH][32][64];   // 49152 B
    __shared__ float adjbuf[32][68];               //  8704 B
    __shared__ float lsebuf[64 * NH];              //  3072 B
    __shared__ float hw[NH][12];                   //   576 B
    const int t = threadIdx.x;
    if (t < NH * 12) hw[t / 12][t % 12] = HwG[t];
    const int lane = t & 63, wave = t >> 6;
    const int quad = lane >> 4, col = lane & 15;
    const int rsub = wave >> 2, csub = wave & 3;
    const int n0 = csub * 16;
    const int rt0 = blockIdx.x * 32;
    const int rbase = rt0 + rsub * 16;       // this wave's 16 rows
    const int cstart = blockIdx.y * seg_len;

    f32x4 invb[3];
    #pragma unroll
    for (int j = 0; j < 3; j++)
        #pragma unroll
        for (int c = 0; c < 4; c++) invb[j][c] = 1.f / betas[j*4 + c];

    bf16x8 af[NH][2];
    {
        const int arow = rbase + col;
        #pragma unroll
        for (int h = 0; h < NH; h++)
            #pragma unroll
            for (int kk = 0; kk < 2; kk++)
                af[h][kk] = *(const bf16x8*)&rowmat[(size_t)arow * CDIM + h*HD + kk*32 + quad*8];
    }
    f32x4 lrow[4][3];
    if (MODE == 0){
        #pragma unroll
        for (int r = 0; r < 4; r++)
            #pragma unroll
            for (int j = 0; j < 3; j++)
                lrow[r][j] = *(const f32x4*)&lse_ws[(size_t)(rbase + quad*4 + r) * NH + j*4];
    }
    f32x4 accB[3][4];
    #pragma unroll
    for (int hh = 0; hh < 3; hh++)
        #pragma unroll
        for (int zt = 0; zt < 4; zt++)
            accB[hh][zt] = (f32x4){0.f,0.f,0.f,0.f};

    for (int cb = cstart; cb < cstart + seg_len; cb += 64){
        __syncthreads();
        #pragma unroll
        for (int i = 0; i < 12; i++){
            const int idx = t + 512 * i;
            const int row = idx / 96, cc = (idx % 96) * 8;
            // swizzled store: logical channel c lives at c ^ ((row>>3 & 3)<<3)
            *(bf16x8*)&colbuf[row][cc ^ (((row >> 3) & 3) << 3)] =
                *(const bf16x8*)&colmat[(size_t)(cb + row) * CDIM + cc];
        }
        if (MODE == 0){
            const int m = t >> 4, nc = (t & 15) * 4;
            f32x4 a = *(const f32x4*)&adj[(size_t)(rt0 + m) * N_TOK + cb + nc];
            adjbuf[m][nc+0] = a[0]; adjbuf[m][nc+1] = a[1];
            adjbuf[m][nc+2] = a[2]; adjbuf[m][nc+3] = a[3];
        } else {
            const int qr = t >> 3, kc = (t & 7) * 4;
            f32x4 a = *(const f32x4*)&adj[(size_t)(cb + qr) * N_TOK + rt0 + kc];
            adjbuf[kc+0][qr] = a[0]; adjbuf[kc+1][qr] = a[1];
            adjbuf[kc+2][qr] = a[2]; adjbuf[kc+3][qr] = a[3];
        }
        if (MODE == 1 && t < 192)
            *(f32x4*)&lsebuf[t*4] = *(const f32x4*)&lse_ws[(size_t)cb * NH + t*4];
        __syncthreads();

        // ---- phase A: this wave's 16 rows x 16 cols (csub subtile) ----
        {
            const int tA = n0 + col;
            const int swzA = ((tA >> 3) & 3) << 3;
            f32x4 G[4][3];
            #pragma unroll
            for (int r = 0; r < 4; r++)
                #pragma unroll
                for (int j = 0; j < 3; j++)
                    G[r][j] = (f32x4){0.f,0.f,0.f,0.f};
            #pragma unroll
            for (int h = 0; h < NH; h++){
                bf16x8 b0 = *(const bf16x8*)&colbuf[tA][(h*HD + quad*8) ^ swzA];
                bf16x8 b1 = *(const bf16x8*)&colbuf[tA][(h*HD + 32 + quad*8) ^ swzA];
                f32x4 s = {0.f,0.f,0.f,0.f};
                s = __builtin_amdgcn_mfma_f32_16x16x32_bf16(af[h][0], b0, s, 0, 0, 0);
                s = __builtin_amdgcn_mfma_f32_16x16x32_bf16(af[h][1], b1, s, 0, 0, 0);
                f32x4 w0 = *(const f32x4*)&hw[h][0];
                f32x4 w1 = *(const f32x4*)&hw[h][4];
                f32x4 w2 = *(const f32x4*)&hw[h][8];
                #pragma unroll
                for (int r = 0; r < 4; r++){
                    G[r][0] += s[r] * w0;
                    G[r][1] += s[r] * w1;
                    G[r][2] += s[r] * w2;
                }
            }
            // convert t-values -> gradient G = -(1/b')*P
            #pragma unroll
            for (int r = 0; r < 4; r++){
                const float adjv = adjbuf[rsub*16 + quad*4 + r][tA];
                f32x4 lv0, lv1, lv2;
                if (MODE == 0){ lv0 = lrow[r][0]; lv1 = lrow[r][1]; lv2 = lrow[r][2]; }
                else {
                    lv0 = *(const f32x4*)&lsebuf[tA * NH + 0];
                    lv1 = *(const f32x4*)&lsebuf[tA * NH + 4];
                    lv2 = *(const f32x4*)&lsebuf[tA * NH + 8];
                }
                f32x4 lv[3] = { lv0, lv1, lv2 };
                #pragma unroll
                for (int j = 0; j < 3; j++)
                    #pragma unroll
                    for (int c = 0; c < 4; c++){
                        const float mm = G[r][j][c] * adjv;
                        const float p  = (mm != 0.f) ? __expf(mm - lv[j][c]) : 0.f;
                        G[r][j][c] = -invb[j][c] * p;
                    }
            }
            // dS = G @ Hw^T, bf16 into dsbuf (swizzled: t' = t ^ ((m&7)<<3))
            #pragma unroll
            for (int h = 0; h < NH; h++){
                f32x4 w0 = *(const f32x4*)&hw[h][0];
                f32x4 w1 = *(const f32x4*)&hw[h][4];
                f32x4 w2 = *(const f32x4*)&hw[h][8];
                #pragma unroll
                for (int r = 0; r < 4; r++){
                    f32x4 pr = G[r][0]*w0 + G[r][1]*w1 + G[r][2]*w2;
                    const float d = pr[0] + pr[1] + pr[2] + pr[3];
                    const int m = rsub*16 + quad*4 + r;
                    dsbuf[h][m][tA ^ ((m & 7) << 3)] = f2bf(d);
                }
            }
        }
        __syncthreads();

        // ---- phase B: dRow[m][z] += sum_kk dS[m][kk] * colmat[kk][z] ----
        #pragma unroll
        for (int hh = 0; hh < 3; hh++){
            const int h = csub + hh*4;
            #pragma unroll
            for (int ks = 0; ks < 2; ks++){
                const int mA = rsub*16 + col;
                bf16x8 a = *(const bf16x8*)&dsbuf[h][mA][(ks*32 + quad*8) ^ ((col & 7) << 3)];
                #pragma unroll
                for (int zt = 0; zt < 4; zt++){
                    const int ch = (h*HD + zt*16 + col) ^ (quad << 3);  // gather swizzle
                    bf16x8 b;
                    #pragma unroll
                    for (int jj = 0; jj < 8; jj++)
                        b[jj] = (short)colbuf[ks*32 + quad*8 + jj][ch];
                    accB[hh][zt] = __builtin_amdgcn_mfma_f32_16x16x32_bf16(a, b, accB[hh][zt], 0, 0, 0);
                }
            }
        }
    }
    float* outp = out_part + (size_t)blockIdx.y * N_TOK * CDIM;
    #pragma unroll
    for (int hh = 0; hh < 3; hh++){
        const int h = csub + hh*4;
        #pragma unroll
        for (int zt = 0; zt < 4; zt++)
            #pragma unroll
            for (int r = 0; r < 4; r++)
                outp[(size_t)(rbase + quad*4 + r) * CDIM + h*HD + zt*16 + col] = accB[hh][zt][r];
    }
}

// ---------------------------------------------------------------------------
// final: dg[n][d] = sum_c beta[c/64]*dQb[n][c]*Wq[c][d] + dKh[n][c]*Wk[c][d]
// ---------------------------------------------------------------------------
__global__ __launch_bounds__(256) void final_dg_kernel(
    const float* __restrict__ dQbp, const float* __restrict__ dKhp,
    const float* __restrict__ Wq, const float* __restrict__ Wk,
    const float* __restrict__ betas, float* __restrict__ dg, int nseg)
{
    __shared__ float at[16][68];
    __shared__ float bt[16][68];
    const int n0 = blockIdx.x * 64, d0 = blockIdx.y * 64;
    const int t  = threadIdx.x;
    const int tx = t & 15, ty = t >> 4;
    const int lr = t >> 2, lk = (t & 3) * 4;
    float acc[4][4] = {};
    for (int src = 0; src < 2; src++){
        const float* P = src ? dKhp : dQbp;
        const float* W = src ? Wk  : Wq;
        for (int c0 = 0; c0 < CDIM; c0 += 16){
            __syncthreads();
            f32x4 a = {0.f,0.f,0.f,0.f};
            for (int s = 0; s < nseg; s++)
                a += *(const f32x4*)&P[((size_t)s * N_TOK + n0 + lr) * CDIM + c0 + lk];
            if (src == 0){
                const float bs = betas[(c0 + lk) >> 6];
                a *= bs;
            }
            at[lk+0][lr] = a[0]; at[lk+1][lr] = a[1]; at[lk+2][lr] = a[2]; at[lk+3][lr] = a[3];
            {
                const int kk = t >> 4, dd = (t & 15) * 4;
                f32x4 wv = *(const f32x4*)&W[(size_t)(c0 + kk) * DIM_IN + d0 + dd];
                bt[kk][dd+0] = wv[0]; bt[kk][dd+1] = wv[1]; bt[kk][dd+2] = wv[2]; bt[kk][dd+3] = wv[3];
            }
            __syncthreads();
            #pragma unroll
            for (int kk = 0; kk < 16; kk++){
                f32x4 av = *(const f32x4*)&at[kk][ty*4];
                f32x4 bv = *(const f32x4*)&bt[kk][tx*4];
                #pragma unroll
                for (int i = 0; i < 4; i++)
                    #pragma unroll
                    for (int j = 0; j < 4; j++)
                        acc[i][j] += av[i] * bv[j];
            }
        }
    }
    #pragma unroll
    for (int i = 0; i < 4; i++)
        #pragma unroll
        for (int j = 0; j < 4; j++)
            dg[(size_t)(n0 + ty*4 + i) * DIM_IN + d0 + tx*4 + j] = acc[i][j];
}

// ---------------------------------------------------------------------------
extern "C" void kernel_launch(void* const* d_in, const int* in_sizes, int n_in,
                              void* d_out, int out_size, void* d_ws, size_t ws_size,
                              hipStream_t stream)
{
    const float* g     = (const float*)d_in[0];
    const float* adj   = (const float*)d_in[1];
    const float* Wk    = (const float*)d_in[2];
    const float* Wq    = (const float*)d_in[3];
    const float* Hw    = (const float*)d_in[4];
    const float* Bk    = (const float*)d_in[5];
    const float* Bq    = (const float*)d_in[6];
    const float* betas = (const float*)d_in[7];
    float* out = (float*)d_out;

    char* ws = (char*)d_ws;
    const size_t szQb   = (size_t)N_TOK * CDIM * sizeof(unsigned short); // 6291456
    const size_t szL    = (size_t)N_TOK * NH * sizeof(float);            // 196608
    const size_t szPart = (size_t)N_TOK * CDIM * sizeof(float);          // 12582912

    unsigned short* Qb = (unsigned short*)(ws);
    unsigned short* Kh = (unsigned short*)(ws + szQb);
    float* l_ws   = (float*)(ws + 2*szQb);
    float* lse_ws = (float*)(ws + 2*szQb + szL);
    char*  parts  = ws + 2*szQb + 2*szL;
    const size_t base = 2*szQb + 2*szL;

    int KS = 1;
    if      (ws_size >= base + 8*szPart) KS = 4;
    else if (ws_size >= base + 4*szPart) KS = 2;
    float* dQbp = (float*)parts;
    float* dKhp = (float*)(parts + (size_t)KS * szPart);

    hipMemsetAsync(l_ws, 0, szL, stream);
    hipMemsetAsync(d_out, 0, sizeof(float), stream);

    proj_kernel<<<dim3(64, 12), 256, 0, stream>>>(g, Wq, Bq, betas, Qb);
    proj_kernel<<<dim3(64, 12), 256, 0, stream>>>(g, Wk, Bk, nullptr, Kh);
    fwd_kernel<<<dim3(64, 8), 256, 0, stream>>>(Qb, Kh, adj, Hw, l_ws, N_TOK / 8);
    lse_energy_kernel<<<dim3(192), 256, 0, stream>>>(l_ws, lse_ws, betas, out);
    bwd_kernel<0><<<dim3(128, KS), 512, 0, stream>>>(Qb, Kh, adj, Hw, lse_ws, betas,
                                                     dQbp, N_TOK / KS);
    bwd_kernel<1><<<dim3(128, KS), 512, 0, stream>>>(Kh, Qb, adj, Hw, lse_ws, betas,
                                                     dKhp, N_TOK / KS);
    final_dg_kernel<<<dim3(64, 8), 256, 0, stream>>>(dQbp, dKhp, Wq, Wk, betas,
                                                     out + 1, KS);
}

// Round 3
// 1997.714 us; speedup vs baseline: 1.6363x; 1.1017x over previous
//
#include <hip/hip_runtime.h>
#include <stdint.h>

#define N_TOK 4096
#define DIM_IN 512
#define NH 12
#define HD 64
#define CDIM 768   // NH*HD

using f32x4  = __attribute__((ext_vector_type(4))) float;
using bf16x8 = __attribute__((ext_vector_type(8))) short;

static __device__ __forceinline__ unsigned short f2bf(float f){
    union { float f; unsigned int u; } v; v.f = f;
    unsigned int r = v.u + 0x7fffu + ((v.u >> 16) & 1u);
    return (unsigned short)(r >> 16);
}

// ---------------------------------------------------------------------------
// proj: out[n][c] = (sum_d g[n][d]*W[c][d] + B[c]) * (scale ? scale[c/64] : 1)
// stored as bf16.  64x64 tile, BK=16, 256 threads, 4x4 micro.
// ---------------------------------------------------------------------------
__global__ __launch_bounds__(256) void proj_kernel(
    const float* __restrict__ g, const float* __restrict__ W,
    const float* __restrict__ B, const float* __restrict__ scale,
    unsigned short* __restrict__ out)
{
    __shared__ float at[16][68];
    __shared__ float bt[16][68];
    const int n0 = blockIdx.x * 64, c0 = blockIdx.y * 64;
    const int t  = threadIdx.x;
    const int tx = t & 15, ty = t >> 4;
    const int lr = t >> 2, lk = (t & 3) * 4;
    float acc[4][4] = {};
    for (int d0 = 0; d0 < DIM_IN; d0 += 16){
        __syncthreads();
        f32x4 gv = *(const f32x4*)&g[(size_t)(n0 + lr) * DIM_IN + d0 + lk];
        at[lk+0][lr] = gv[0]; at[lk+1][lr] = gv[1]; at[lk+2][lr] = gv[2]; at[lk+3][lr] = gv[3];
        f32x4 wv = *(const f32x4*)&W[(size_t)(c0 + lr) * DIM_IN + d0 + lk];
        bt[lk+0][lr] = wv[0]; bt[lk+1][lr] = wv[1]; bt[lk+2][lr] = wv[2]; bt[lk+3][lr] = wv[3];
        __syncthreads();
        #pragma unroll
        for (int kk = 0; kk < 16; kk++){
            f32x4 av = *(const f32x4*)&at[kk][ty*4];
            f32x4 bv = *(const f32x4*)&bt[kk][tx*4];
            #pragma unroll
            for (int i = 0; i < 4; i++)
                #pragma unroll
                for (int j = 0; j < 4; j++)
                    acc[i][j] += av[i] * bv[j];
        }
    }
    #pragma unroll
    for (int i = 0; i < 4; i++){
        const int n = n0 + ty*4 + i;
        #pragma unroll
        for (int j = 0; j < 4; j++){
            const int c = c0 + tx*4 + j;
            float v = acc[i][j] + B[c];
            if (scale) v *= scale[c >> 6];
            out[(size_t)n * CDIM + c] = f2bf(v);
        }
    }
}

// ---------------------------------------------------------------------------
// forward: per 16x16 (q,k) MFMA tile, 12 head scores -> Hw mix -> adj mask ->
// accumulate sum(exp) per (q-row, h').  atomicAdd partials into l_ws.
// ---------------------------------------------------------------------------
#define TKF 32
#define KBS 776   // ushort stride: 1552 B (16B aligned, 2-way-bank only)

__global__ __launch_bounds__(256, 2) void fwd_kernel(
    const unsigned short* __restrict__ Qb, const unsigned short* __restrict__ Kh,
    const float* __restrict__ adj, const float* __restrict__ HwG,
    float* __restrict__ l_ws, int seg_len)
{
    __shared__ unsigned short kbuf[TKF][KBS];
    __shared__ float hw[NH][12];
    const int t = threadIdx.x;
    if (t < NH * 12) hw[t / 12][t % 12] = HwG[t];
    const int lane = t & 63, wave = t >> 6;
    const int quad = lane >> 4, col = lane & 15;
    const int qt0 = blockIdx.x * 64 + wave * 16;
    const int kstart = blockIdx.y * seg_len;

    bf16x8 af[NH][2];
    {
        const int arow = qt0 + col;
        #pragma unroll
        for (int h = 0; h < NH; h++)
            #pragma unroll
            for (int kk = 0; kk < 2; kk++)
                af[h][kk] = *(const bf16x8*)&Qb[(size_t)arow * CDIM + h*HD + kk*32 + quad*8];
    }
    f32x4 l4[4][3];
    #pragma unroll
    for (int r = 0; r < 4; r++)
        #pragma unroll
        for (int j = 0; j < 3; j++)
            l4[r][j] = (f32x4){0.f,0.f,0.f,0.f};

    for (int kc = kstart; kc < kstart + seg_len; kc += TKF){
        __syncthreads();
        #pragma unroll
        for (int i = 0; i < 12; i++){
            const int idx = t + 256 * i;
            const int row = idx / 96, cc = (idx % 96) * 8;
            *(bf16x8*)&kbuf[row][cc] = *(const bf16x8*)&Kh[(size_t)(kc + row) * CDIM + cc];
        }
        __syncthreads();
        #pragma unroll
        for (int sub = 0; sub < 2; sub++){
            const int k0 = kc + sub * 16;
            f32x4 tv[4][3];
            #pragma unroll
            for (int r = 0; r < 4; r++)
                #pragma unroll
                for (int j = 0; j < 3; j++)
                    tv[r][j] = (f32x4){0.f,0.f,0.f,0.f};
            #pragma unroll
            for (int h = 0; h < NH; h++){
                bf16x8 b0 = *(const bf16x8*)&kbuf[sub*16 + col][h*HD + quad*8];
                bf16x8 b1 = *(const bf16x8*)&kbuf[sub*16 + col][h*HD + 32 + quad*8];
                f32x4 s = {0.f,0.f,0.f,0.f};
                s = __builtin_amdgcn_mfma_f32_16x16x32_bf16(af[h][0], b0, s, 0, 0, 0);
                s = __builtin_amdgcn_mfma_f32_16x16x32_bf16(af[h][1], b1, s, 0, 0, 0);
                f32x4 w0 = *(const f32x4*)&hw[h][0];
                f32x4 w1 = *(const f32x4*)&hw[h][4];
                f32x4 w2 = *(const f32x4*)&hw[h][8];
                #pragma unroll
                for (int r = 0; r < 4; r++){
                    tv[r][0] += s[r] * w0;
                    tv[r][1] += s[r] * w1;
                    tv[r][2] += s[r] * w2;
                }
            }
            #pragma unroll
            for (int r = 0; r < 4; r++){
                const float adjv = adj[(size_t)(qt0 + quad*4 + r) * N_TOK + k0 + col];
                #pragma unroll
                for (int j = 0; j < 3; j++){
                    #pragma unroll
                    for (int c = 0; c < 4; c++){
                        const float mm = tv[r][j][c] * adjv;   // matches T*adj
                        if (mm != 0.f) l4[r][j][c] += __expf(mm);
                    }
                }
            }
        }
    }
    #pragma unroll
    for (int r = 0; r < 4; r++)
        #pragma unroll
        for (int j = 0; j < 3; j++)
            #pragma unroll
            for (int c = 0; c < 4; c++){
                float v = l4[r][j][c];
                v += __shfl_xor(v, 1, 16);
                v += __shfl_xor(v, 2, 16);
                v += __shfl_xor(v, 4, 16);
                v += __shfl_xor(v, 8, 16);
                if (col == j*4 + c)
                    atomicAdd(&l_ws[(size_t)(qt0 + quad*4 + r) * NH + (j*4 + c)], v);
            }
}

// ---------------------------------------------------------------------------
// lse + energy
// ---------------------------------------------------------------------------
__global__ __launch_bounds__(256) void lse_energy_kernel(
    const float* __restrict__ l_ws, float* __restrict__ lse_ws,
    const float* __restrict__ betas, float* __restrict__ energy)
{
    const int t = threadIdx.x;
    const int i = blockIdx.x * 256 + t;
    const float l = l_ws[i];
    float lse, ep;
    if (l > 0.f){ lse = logf(l); ep = -(1.f / betas[i % NH]) * lse; }
    else        { lse = -1e30f; ep = 0.f; }
    lse_ws[i] = lse;
    __shared__ float red[256];
    red[t] = ep;
    __syncthreads();
    for (int s = 128; s > 0; s >>= 1){
        if (t < s) red[t] += red[t + s];
        __syncthreads();
    }
    if (t == 0) atomicAdd(energy, red[0]);
}

// ---------------------------------------------------------------------------
// backward: 512 threads / 8 waves per block, 32-row tile, 64-col chunks.
// Register-budget model (measured r0-r2): VGPR file = 512/lane total
// (arch+acc unified); cap = 512 / (waves/EU).  8-wave block @ 1 block/CU
// = 2 waves/EU -> cap 256.  Demand was ~300 (spilled ~50 regs -> 1.4 GB
// scratch FETCH in r2).  Cuts here: lrow (48) -> rowlse LDS, invb (12) ->
// invbuf LDS; demand now ~240 <= 256.  Budget pinned explicitly via
// amdgpu_waves_per_eu(2,2) instead of __launch_bounds__ 2nd-arg guesswork.
// LDS: mode0 159,344 B / mode1 160,880 B <= 163,840 (1 block/CU).
// ---------------------------------------------------------------------------
#define CBS 776   // colbuf ushort stride

template<int MODE>
__global__ __attribute__((amdgpu_flat_work_group_size(512, 512), amdgpu_waves_per_eu(2, 2)))
void bwd_kernel(
    const unsigned short* __restrict__ rowmat, const unsigned short* __restrict__ colmat,
    const float* __restrict__ adj, const float* __restrict__ HwG,
    const float* __restrict__ lse_ws, const float* __restrict__ betas,
    float* __restrict__ out_part, int seg_len)
{
    __shared__ unsigned short colbuf[64][CBS];     // 99328 B
    __shared__ unsigned short dsbuf[NH][32][64];   // 49152 B
    __shared__ float adjbuf[32][68];               //  8704 B
    __shared__ float lsebuf[64 * NH];              //  3072 B (mode 1 only)
    __shared__ float rowlse[32 * NH];              //  1536 B (mode 0 only)
    __shared__ float invbuf[NH];                   //    48 B
    __shared__ float hw[NH][12];                   //   576 B
    const int t = threadIdx.x;
    if (t < NH * 12) hw[t / 12][t % 12] = HwG[t];
    if (t < NH) invbuf[t] = 1.f / betas[t];
    const int lane = t & 63, wave = t >> 6;
    const int quad = lane >> 4, col = lane & 15;
    const int rsub = wave >> 2, csub = wave & 3;
    const int n0 = csub * 16;
    const int rt0 = blockIdx.x * 32;
    const int rbase = rt0 + rsub * 16;       // this wave's 16 rows
    const int cstart = blockIdx.y * seg_len;

    if (MODE == 0 && t < 96)
        *(f32x4*)&rowlse[t*4] = *(const f32x4*)&lse_ws[(size_t)rt0 * NH + t*4];

    bf16x8 af[NH][2];
    {
        const int arow = rbase + col;
        #pragma unroll
        for (int h = 0; h < NH; h++)
            #pragma unroll
            for (int kk = 0; kk < 2; kk++)
                af[h][kk] = *(const bf16x8*)&rowmat[(size_t)arow * CDIM + h*HD + kk*32 + quad*8];
    }
    f32x4 accB[3][4];
    #pragma unroll
    for (int hh = 0; hh < 3; hh++)
        #pragma unroll
        for (int zt = 0; zt < 4; zt++)
            accB[hh][zt] = (f32x4){0.f,0.f,0.f,0.f};

    for (int cb = cstart; cb < cstart + seg_len; cb += 64){
        __syncthreads();
        #pragma unroll
        for (int i = 0; i < 12; i++){
            const int idx = t + 512 * i;
            const int row = idx / 96, cc = (idx % 96) * 8;
            // swizzled store: logical channel c lives at c ^ ((row>>3 & 3)<<3)
            *(bf16x8*)&colbuf[row][cc ^ (((row >> 3) & 3) << 3)] =
                *(const bf16x8*)&colmat[(size_t)(cb + row) * CDIM + cc];
        }
        if (MODE == 0){
            const int m = t >> 4, nc = (t & 15) * 4;
            f32x4 a = *(const f32x4*)&adj[(size_t)(rt0 + m) * N_TOK + cb + nc];
            adjbuf[m][nc+0] = a[0]; adjbuf[m][nc+1] = a[1];
            adjbuf[m][nc+2] = a[2]; adjbuf[m][nc+3] = a[3];
        } else {
            const int qr = t >> 3, kc = (t & 7) * 4;
            f32x4 a = *(const f32x4*)&adj[(size_t)(cb + qr) * N_TOK + rt0 + kc];
            adjbuf[kc+0][qr] = a[0]; adjbuf[kc+1][qr] = a[1];
            adjbuf[kc+2][qr] = a[2]; adjbuf[kc+3][qr] = a[3];
        }
        if (MODE == 1 && t < 192)
            *(f32x4*)&lsebuf[t*4] = *(const f32x4*)&lse_ws[(size_t)cb * NH + t*4];
        __syncthreads();

        // ---- phase A: this wave's 16 rows x 16 cols (csub subtile) ----
        {
            const int tA = n0 + col;
            const int swzA = ((tA >> 3) & 3) << 3;
            f32x4 G[4][3];
            #pragma unroll
            for (int r = 0; r < 4; r++)
                #pragma unroll
                for (int j = 0; j < 3; j++)
                    G[r][j] = (f32x4){0.f,0.f,0.f,0.f};
            #pragma unroll
            for (int h = 0; h < NH; h++){
                bf16x8 b0 = *(const bf16x8*)&colbuf[tA][(h*HD + quad*8) ^ swzA];
                bf16x8 b1 = *(const bf16x8*)&colbuf[tA][(h*HD + 32 + quad*8) ^ swzA];
                f32x4 s = {0.f,0.f,0.f,0.f};
                s = __builtin_amdgcn_mfma_f32_16x16x32_bf16(af[h][0], b0, s, 0, 0, 0);
                s = __builtin_amdgcn_mfma_f32_16x16x32_bf16(af[h][1], b1, s, 0, 0, 0);
                f32x4 w0 = *(const f32x4*)&hw[h][0];
                f32x4 w1 = *(const f32x4*)&hw[h][4];
                f32x4 w2 = *(const f32x4*)&hw[h][8];
                #pragma unroll
                for (int r = 0; r < 4; r++){
                    G[r][0] += s[r] * w0;
                    G[r][1] += s[r] * w1;
                    G[r][2] += s[r] * w2;
                }
            }
            // convert t-values -> gradient G = -(1/b')*P   (lse + 1/beta from LDS)
            #pragma unroll
            for (int r = 0; r < 4; r++){
                const float adjv = adjbuf[rsub*16 + quad*4 + r][tA];
                #pragma unroll
                for (int j = 0; j < 3; j++){
                    f32x4 lv;
                    if (MODE == 0) lv = *(const f32x4*)&rowlse[(rsub*16 + quad*4 + r) * NH + j*4];
                    else           lv = *(const f32x4*)&lsebuf[tA * NH + j*4];
                    #pragma unroll
                    for (int c = 0; c < 4; c++){
                        const float mm = G[r][j][c] * adjv;
                        const float p  = (mm != 0.f) ? __expf(mm - lv[c]) : 0.f;
                        G[r][j][c] = -invbuf[j*4 + c] * p;
                    }
                }
            }
            // dS = G @ Hw^T, bf16 into dsbuf (swizzled: t' = t ^ ((m&7)<<3))
            #pragma unroll
            for (int h = 0; h < NH; h++){
                f32x4 w0 = *(const f32x4*)&hw[h][0];
                f32x4 w1 = *(const f32x4*)&hw[h][4];
                f32x4 w2 = *(const f32x4*)&hw[h][8];
                #pragma unroll
                for (int r = 0; r < 4; r++){
                    f32x4 pr = G[r][0]*w0 + G[r][1]*w1 + G[r][2]*w2;
                    const float d = pr[0] + pr[1] + pr[2] + pr[3];
                    const int m = rsub*16 + quad*4 + r;
                    dsbuf[h][m][tA ^ ((m & 7) << 3)] = f2bf(d);
                }
            }
        }
        __syncthreads();

        // ---- phase B: dRow[m][z] += sum_kk dS[m][kk] * colmat[kk][z] ----
        #pragma unroll
        for (int hh = 0; hh < 3; hh++){
            const int h = csub + hh*4;
            #pragma unroll
            for (int ks = 0; ks < 2; ks++){
                const int mA = rsub*16 + col;
                bf16x8 a = *(const bf16x8*)&dsbuf[h][mA][(ks*32 + quad*8) ^ ((col & 7) << 3)];
                #pragma unroll
                for (int zt = 0; zt < 4; zt++){
                    const int ch = (h*HD + zt*16 + col) ^ (quad << 3);  // gather swizzle
                    bf16x8 b;
                    #pragma unroll
                    for (int jj = 0; jj < 8; jj++)
                        b[jj] = (short)colbuf[ks*32 + quad*8 + jj][ch];
                    accB[hh][zt] = __builtin_amdgcn_mfma_f32_16x16x32_bf16(a, b, accB[hh][zt], 0, 0, 0);
                }
            }
        }
    }
    float* outp = out_part + (size_t)blockIdx.y * N_TOK * CDIM;
    #pragma unroll
    for (int hh = 0; hh < 3; hh++){
        const int h = csub + hh*4;
        #pragma unroll
        for (int zt = 0; zt < 4; zt++)
            #pragma unroll
            for (int r = 0; r < 4; r++)
                outp[(size_t)(rbase + quad*4 + r) * CDIM + h*HD + zt*16 + col] = accB[hh][zt][r];
    }
}

// ---------------------------------------------------------------------------
// final: dg[n][d] = sum_c beta[c/64]*dQb[n][c]*Wq[c][d] + dKh[n][c]*Wk[c][d]
// ---------------------------------------------------------------------------
__global__ __launch_bounds__(256) void final_dg_kernel(
    const float* __restrict__ dQbp, const float* __restrict__ dKhp,
    const float* __restrict__ Wq, const float* __restrict__ Wk,
    const float* __restrict__ betas, float* __restrict__ dg, int nseg)
{
    __shared__ float at[16][68];
    __shared__ float bt[16][68];
    const int n0 = blockIdx.x * 64, d0 = blockIdx.y * 64;
    const int t  = threadIdx.x;
    const int tx = t & 15, ty = t >> 4;
    const int lr = t >> 2, lk = (t & 3) * 4;
    float acc[4][4] = {};
    for (int src = 0; src < 2; src++){
        const float* P = src ? dKhp : dQbp;
        const float* W = src ? Wk  : Wq;
        for (int c0 = 0; c0 < CDIM; c0 += 16){
            __syncthreads();
            f32x4 a = {0.f,0.f,0.f,0.f};
            for (int s = 0; s < nseg; s++)
                a += *(const f32x4*)&P[((size_t)s * N_TOK + n0 + lr) * CDIM + c0 + lk];
            if (src == 0){
                const float bs = betas[(c0 + lk) >> 6];
                a *= bs;
            }
            at[lk+0][lr] = a[0]; at[lk+1][lr] = a[1]; at[lk+2][lr] = a[2]; at[lk+3][lr] = a[3];
            {
                const int kk = t >> 4, dd = (t & 15) * 4;
                f32x4 wv = *(const f32x4*)&W[(size_t)(c0 + kk) * DIM_IN + d0 + dd];
                bt[kk][dd+0] = wv[0]; bt[kk][dd+1] = wv[1]; bt[kk][dd+2] = wv[2]; bt[kk][dd+3] = wv[3];
            }
            __syncthreads();
            #pragma unroll
            for (int kk = 0; kk < 16; kk++){
                f32x4 av = *(const f32x4*)&at[kk][ty*4];
                f32x4 bv = *(const f32x4*)&bt[kk][tx*4];
                #pragma unroll
                for (int i = 0; i < 4; i++)
                    #pragma unroll
                    for (int j = 0; j < 4; j++)
                        acc[i][j] += av[i] * bv[j];
            }
        }
    }
    #pragma unroll
    for (int i = 0; i < 4; i++)
        #pragma unroll
        for (int j = 0; j < 4; j++)
            dg[(size_t)(n0 + ty*4 + i) * DIM_IN + d0 + tx*4 + j] = acc[i][j];
}

// ---------------------------------------------------------------------------
extern "C" void kernel_launch(void* const* d_in, const int* in_sizes, int n_in,
                              void* d_out, int out_size, void* d_ws, size_t ws_size,
                              hipStream_t stream)
{
    const float* g     = (const float*)d_in[0];
    const float* adj   = (const float*)d_in[1];
    const float* Wk    = (const float*)d_in[2];
    const float* Wq    = (const float*)d_in[3];
    const float* Hw    = (const float*)d_in[4];
    const float* Bk    = (const float*)d_in[5];
    const float* Bq    = (const float*)d_in[6];
    const float* betas = (const float*)d_in[7];
    float* out = (float*)d_out;

    char* ws = (char*)d_ws;
    const size_t szQb   = (size_t)N_TOK * CDIM * sizeof(unsigned short); // 6291456
    const size_t szL    = (size_t)N_TOK * NH * sizeof(float);            // 196608
    const size_t szPart = (size_t)N_TOK * CDIM * sizeof(float);          // 12582912

    unsigned short* Qb = (unsigned short*)(ws);
    unsigned short* Kh = (unsigned short*)(ws + szQb);
    float* l_ws   = (float*)(ws + 2*szQb);
    float* lse_ws = (float*)(ws + 2*szQb + szL);
    char*  parts  = ws + 2*szQb + 2*szL;
    const size_t base = 2*szQb + 2*szL;

    int KS = 1;
    if      (ws_size >= base + 8*szPart) KS = 4;
    else if (ws_size >= base + 4*szPart) KS = 2;
    float* dQbp = (float*)parts;
    float* dKhp = (float*)(parts + (size_t)KS * szPart);

    hipMemsetAsync(l_ws, 0, szL, stream);
    hipMemsetAsync(d_out, 0, sizeof(float), stream);

    proj_kernel<<<dim3(64, 12), 256, 0, stream>>>(g, Wq, Bq, betas, Qb);
    proj_kernel<<<dim3(64, 12), 256, 0, stream>>>(g, Wk, Bk, nullptr, Kh);
    fwd_kernel<<<dim3(64, 8), 256, 0, stream>>>(Qb, Kh, adj, Hw, l_ws, N_TOK / 8);
    lse_energy_kernel<<<dim3(192), 256, 0, stream>>>(l_ws, lse_ws, betas, out);
    bwd_kernel<0><<<dim3(128, KS), 512, 0, stream>>>(Qb, Kh, adj, Hw, lse_ws, betas,
                                                     dQbp, N_TOK / KS);
    bwd_kernel<1><<<dim3(128, KS), 512, 0, stream>>>(Kh, Qb, adj, Hw, lse_ws, betas,
                                                     dKhp, N_TOK / KS);
    final_dg_kernel<<<dim3(64, 8), 256, 0, stream>>>(dQbp, dKhp, Wq, Wk, betas,
                                                     out + 1, KS);
}

// Round 4
// 1791.635 us; speedup vs baseline: 1.8245x; 1.1150x over previous
//
#include <hip/hip_runtime.h>
#include <stdint.h>

#define N_TOK 4096
#define DIM_IN 512
#define NH 12
#define HD 64
#define CDIM 768   // NH*HD

using f32x4  = __attribute__((ext_vector_type(4))) float;
using bf16x8 = __attribute__((ext_vector_type(8))) short;

static __device__ __forceinline__ unsigned short f2bf(float f){
    union { float f; unsigned int u; } v; v.f = f;
    unsigned int r = v.u + 0x7fffu + ((v.u >> 16) & 1u);
    return (unsigned short)(r >> 16);
}

// ---------------------------------------------------------------------------
// proj: out[n][c] = (sum_d g[n][d]*W[c][d] + B[c]) * (scale ? scale[c/64] : 1)
// stored as bf16.  64x64 tile, BK=16, 256 threads, 4x4 micro.
// ---------------------------------------------------------------------------
__global__ __launch_bounds__(256) void proj_kernel(
    const float* __restrict__ g, const float* __restrict__ W,
    const float* __restrict__ B, const float* __restrict__ scale,
    unsigned short* __restrict__ out)
{
    __shared__ float at[16][68];
    __shared__ float bt[16][68];
    const int n0 = blockIdx.x * 64, c0 = blockIdx.y * 64;
    const int t  = threadIdx.x;
    const int tx = t & 15, ty = t >> 4;
    const int lr = t >> 2, lk = (t & 3) * 4;
    float acc[4][4] = {};
    for (int d0 = 0; d0 < DIM_IN; d0 += 16){
        __syncthreads();
        f32x4 gv = *(const f32x4*)&g[(size_t)(n0 + lr) * DIM_IN + d0 + lk];
        at[lk+0][lr] = gv[0]; at[lk+1][lr] = gv[1]; at[lk+2][lr] = gv[2]; at[lk+3][lr] = gv[3];
        f32x4 wv = *(const f32x4*)&W[(size_t)(c0 + lr) * DIM_IN + d0 + lk];
        bt[lk+0][lr] = wv[0]; bt[lk+1][lr] = wv[1]; bt[lk+2][lr] = wv[2]; bt[lk+3][lr] = wv[3];
        __syncthreads();
        #pragma unroll
        for (int kk = 0; kk < 16; kk++){
            f32x4 av = *(const f32x4*)&at[kk][ty*4];
            f32x4 bv = *(const f32x4*)&bt[kk][tx*4];
            #pragma unroll
            for (int i = 0; i < 4; i++)
                #pragma unroll
                for (int j = 0; j < 4; j++)
                    acc[i][j] += av[i] * bv[j];
        }
    }
    #pragma unroll
    for (int i = 0; i < 4; i++){
        const int n = n0 + ty*4 + i;
        #pragma unroll
        for (int j = 0; j < 4; j++){
            const int c = c0 + tx*4 + j;
            float v = acc[i][j] + B[c];
            if (scale) v *= scale[c >> 6];
            out[(size_t)n * CDIM + c] = f2bf(v);
        }
    }
}

// ---------------------------------------------------------------------------
// forward: per 16x16 (q,k) MFMA tile, 12 head scores -> Hw mix -> adj mask ->
// accumulate sum(exp) per (q-row, h').  atomicAdd partials into l_ws.
// ---------------------------------------------------------------------------
#define TKF 32
#define KBS 776   // ushort stride: 1552 B (16B aligned, 2-way-bank only)

__global__ __launch_bounds__(256, 2) void fwd_kernel(
    const unsigned short* __restrict__ Qb, const unsigned short* __restrict__ Kh,
    const float* __restrict__ adj, const float* __restrict__ HwG,
    float* __restrict__ l_ws, int seg_len)
{
    __shared__ unsigned short kbuf[TKF][KBS];
    __shared__ float hw[NH][12];
    const int t = threadIdx.x;
    if (t < NH * 12) hw[t / 12][t % 12] = HwG[t];
    const int lane = t & 63, wave = t >> 6;
    const int quad = lane >> 4, col = lane & 15;
    const int qt0 = blockIdx.x * 64 + wave * 16;
    const int kstart = blockIdx.y * seg_len;

    bf16x8 af[NH][2];
    {
        const int arow = qt0 + col;
        #pragma unroll
        for (int h = 0; h < NH; h++)
            #pragma unroll
            for (int kk = 0; kk < 2; kk++)
                af[h][kk] = *(const bf16x8*)&Qb[(size_t)arow * CDIM + h*HD + kk*32 + quad*8];
    }
    f32x4 l4[4][3];
    #pragma unroll
    for (int r = 0; r < 4; r++)
        #pragma unroll
        for (int j = 0; j < 3; j++)
            l4[r][j] = (f32x4){0.f,0.f,0.f,0.f};

    for (int kc = kstart; kc < kstart + seg_len; kc += TKF){
        __syncthreads();
        #pragma unroll
        for (int i = 0; i < 12; i++){
            const int idx = t + 256 * i;
            const int row = idx / 96, cc = (idx % 96) * 8;
            *(bf16x8*)&kbuf[row][cc] = *(const bf16x8*)&Kh[(size_t)(kc + row) * CDIM + cc];
        }
        __syncthreads();
        #pragma unroll
        for (int sub = 0; sub < 2; sub++){
            const int k0 = kc + sub * 16;
            f32x4 tv[4][3];
            #pragma unroll
            for (int r = 0; r < 4; r++)
                #pragma unroll
                for (int j = 0; j < 3; j++)
                    tv[r][j] = (f32x4){0.f,0.f,0.f,0.f};
            #pragma unroll
            for (int h = 0; h < NH; h++){
                bf16x8 b0 = *(const bf16x8*)&kbuf[sub*16 + col][h*HD + quad*8];
                bf16x8 b1 = *(const bf16x8*)&kbuf[sub*16 + col][h*HD + 32 + quad*8];
                f32x4 s = {0.f,0.f,0.f,0.f};
                s = __builtin_amdgcn_mfma_f32_16x16x32_bf16(af[h][0], b0, s, 0, 0, 0);
                s = __builtin_amdgcn_mfma_f32_16x16x32_bf16(af[h][1], b1, s, 0, 0, 0);
                f32x4 w0 = *(const f32x4*)&hw[h][0];
                f32x4 w1 = *(const f32x4*)&hw[h][4];
                f32x4 w2 = *(const f32x4*)&hw[h][8];
                #pragma unroll
                for (int r = 0; r < 4; r++){
                    tv[r][0] += s[r] * w0;
                    tv[r][1] += s[r] * w1;
                    tv[r][2] += s[r] * w2;
                }
            }
            #pragma unroll
            for (int r = 0; r < 4; r++){
                const float adjv = adj[(size_t)(qt0 + quad*4 + r) * N_TOK + k0 + col];
                #pragma unroll
                for (int j = 0; j < 3; j++){
                    #pragma unroll
                    for (int c = 0; c < 4; c++){
                        const float mm = tv[r][j][c] * adjv;   // matches T*adj
                        if (mm != 0.f) l4[r][j][c] += __expf(mm);
                    }
                }
            }
        }
    }
    #pragma unroll
    for (int r = 0; r < 4; r++)
        #pragma unroll
        for (int j = 0; j < 3; j++)
            #pragma unroll
            for (int c = 0; c < 4; c++){
                float v = l4[r][j][c];
                v += __shfl_xor(v, 1, 16);
                v += __shfl_xor(v, 2, 16);
                v += __shfl_xor(v, 4, 16);
                v += __shfl_xor(v, 8, 16);
                if (col == j*4 + c)
                    atomicAdd(&l_ws[(size_t)(qt0 + quad*4 + r) * NH + (j*4 + c)], v);
            }
}

// ---------------------------------------------------------------------------
// lse + energy
// ---------------------------------------------------------------------------
__global__ __launch_bounds__(256) void lse_energy_kernel(
    const float* __restrict__ l_ws, float* __restrict__ lse_ws,
    const float* __restrict__ betas, float* __restrict__ energy)
{
    const int t = threadIdx.x;
    const int i = blockIdx.x * 256 + t;
    const float l = l_ws[i];
    float lse, ep;
    if (l > 0.f){ lse = logf(l); ep = -(1.f / betas[i % NH]) * lse; }
    else        { lse = -1e30f; ep = 0.f; }
    lse_ws[i] = lse;
    __shared__ float red[256];
    red[t] = ep;
    __syncthreads();
    for (int s = 128; s > 0; s >>= 1){
        if (t < s) red[t] += red[t + s];
        __syncthreads();
    }
    if (t == 0) atomicAdd(energy, red[0]);
}

// ---------------------------------------------------------------------------
// backward: 512 threads / 8 waves per block, 32-row tile, 64-col chunks.
// Register-budget model (r0-r3 measured): 2 waves/EU -> 256 unified regs/lane.
// r3 demand ~300 (af 96 + accB 48 + G 48 + staging 48 + temps) -> ~44 spilled
// -> ~0.9 GB/dispatch scratch FETCH (scratch = per-wave private = real HBM).
// Fix: af[12][2] no longer register-persistent; A-fragments are re-loaded from
// rowmat (global) inside the h-loop each chunk.  Same 48 KB tile every chunk,
// shared across blocks -> L1/L2-served, ~zero HBM, and the Hw-mix VALU hides
// the latency.  The asm "+v" pointer-launder per chunk blocks the compiler
// from hoisting these loop-invariant loads back into a 96-reg array.
// Demand now ~170 <= 256 -> no spill.
// LDS: mode0 159,744 B / mode1 161,280 B <= 163,840 (1 block/CU, 2 waves/EU).
// ---------------------------------------------------------------------------
#define CBS 776   // colbuf ushort stride

template<int MODE>
__global__ __attribute__((amdgpu_flat_work_group_size(512, 512), amdgpu_waves_per_eu(2, 2)))
void bwd_kernel(
    const unsigned short* __restrict__ rowmat, const unsigned short* __restrict__ colmat,
    const float* __restrict__ adj, const float* __restrict__ HwG,
    const float* __restrict__ lse_ws, const float* __restrict__ betas,
    float* __restrict__ out_part, int seg_len)
{
    __shared__ unsigned short colbuf[64][CBS];     // 99328 B
    __shared__ unsigned short dsbuf[NH][32][64];   // 49152 B
    __shared__ float adjbuf[32][68];               //  8704 B
    __shared__ float lsebuf[64 * NH];              //  3072 B (mode 1 only)
    __shared__ float rowlse[32 * NH];              //  1536 B (mode 0 only)
    __shared__ float invbuf[NH];                   //    48 B
    __shared__ float hw[NH][12];                   //   576 B
    const int t = threadIdx.x;
    if (t < NH * 12) hw[t / 12][t % 12] = HwG[t];
    if (t < NH) invbuf[t] = 1.f / betas[t];
    const int lane = t & 63, wave = t >> 6;
    const int quad = lane >> 4, col = lane & 15;
    const int rsub = wave >> 2, csub = wave & 3;
    const int n0 = csub * 16;
    const int rt0 = blockIdx.x * 32;
    const int rbase = rt0 + rsub * 16;       // this wave's 16 rows
    const int cstart = blockIdx.y * seg_len;

    if (MODE == 0 && t < 96)
        *(f32x4*)&rowlse[t*4] = *(const f32x4*)&lse_ws[(size_t)rt0 * NH + t*4];

    // A-fragment source row for this lane (16 B aligned vector loads)
    const unsigned short* rowp = &rowmat[(size_t)(rbase + col) * CDIM + quad*8];

    f32x4 accB[3][4];
    #pragma unroll
    for (int hh = 0; hh < 3; hh++)
        #pragma unroll
        for (int zt = 0; zt < 4; zt++)
            accB[hh][zt] = (f32x4){0.f,0.f,0.f,0.f};

    for (int cb = cstart; cb < cstart + seg_len; cb += 64){
        __syncthreads();
        #pragma unroll
        for (int i = 0; i < 12; i++){
            const int idx = t + 512 * i;
            const int row = idx / 96, cc = (idx % 96) * 8;
            // swizzled store: logical channel c lives at c ^ ((row>>3 & 3)<<3)
            *(bf16x8*)&colbuf[row][cc ^ (((row >> 3) & 3) << 3)] =
                *(const bf16x8*)&colmat[(size_t)(cb + row) * CDIM + cc];
        }
        if (MODE == 0){
            const int m = t >> 4, nc = (t & 15) * 4;
            f32x4 a = *(const f32x4*)&adj[(size_t)(rt0 + m) * N_TOK + cb + nc];
            adjbuf[m][nc+0] = a[0]; adjbuf[m][nc+1] = a[1];
            adjbuf[m][nc+2] = a[2]; adjbuf[m][nc+3] = a[3];
        } else {
            const int qr = t >> 3, kc = (t & 7) * 4;
            f32x4 a = *(const f32x4*)&adj[(size_t)(cb + qr) * N_TOK + rt0 + kc];
            adjbuf[kc+0][qr] = a[0]; adjbuf[kc+1][qr] = a[1];
            adjbuf[kc+2][qr] = a[2]; adjbuf[kc+3][qr] = a[3];
        }
        if (MODE == 1 && t < 192)
            *(f32x4*)&lsebuf[t*4] = *(const f32x4*)&lse_ws[(size_t)cb * NH + t*4];
        __syncthreads();

        // launder the A-row pointer so the per-h loads below cannot be
        // hoisted out of the cb loop (would recreate a 96-reg af array)
        const unsigned short* rp = rowp;
        asm volatile("" : "+v"(rp));

        // ---- phase A: this wave's 16 rows x 16 cols (csub subtile) ----
        {
            const int tA = n0 + col;
            const int swzA = ((tA >> 3) & 3) << 3;
            f32x4 G[4][3];
            #pragma unroll
            for (int r = 0; r < 4; r++)
                #pragma unroll
                for (int j = 0; j < 3; j++)
                    G[r][j] = (f32x4){0.f,0.f,0.f,0.f};
            #pragma unroll
            for (int h = 0; h < NH; h++){
                bf16x8 a0 = *(const bf16x8*)&rp[h*HD];
                bf16x8 a1 = *(const bf16x8*)&rp[h*HD + 32];
                bf16x8 b0 = *(const bf16x8*)&colbuf[tA][(h*HD + quad*8) ^ swzA];
                bf16x8 b1 = *(const bf16x8*)&colbuf[tA][(h*HD + 32 + quad*8) ^ swzA];
                f32x4 s = {0.f,0.f,0.f,0.f};
                s = __builtin_amdgcn_mfma_f32_16x16x32_bf16(a0, b0, s, 0, 0, 0);
                s = __builtin_amdgcn_mfma_f32_16x16x32_bf16(a1, b1, s, 0, 0, 0);
                f32x4 w0 = *(const f32x4*)&hw[h][0];
                f32x4 w1 = *(const f32x4*)&hw[h][4];
                f32x4 w2 = *(const f32x4*)&hw[h][8];
                #pragma unroll
                for (int r = 0; r < 4; r++){
                    G[r][0] += s[r] * w0;
                    G[r][1] += s[r] * w1;
                    G[r][2] += s[r] * w2;
                }
            }
            // convert t-values -> gradient G = -(1/b')*P   (lse + 1/beta from LDS)
            #pragma unroll
            for (int r = 0; r < 4; r++){
                const float adjv = adjbuf[rsub*16 + quad*4 + r][tA];
                #pragma unroll
                for (int j = 0; j < 3; j++){
                    f32x4 lv;
                    if (MODE == 0) lv = *(const f32x4*)&rowlse[(rsub*16 + quad*4 + r) * NH + j*4];
                    else           lv = *(const f32x4*)&lsebuf[tA * NH + j*4];
                    #pragma unroll
                    for (int c = 0; c < 4; c++){
                        const float mm = G[r][j][c] * adjv;
                        const float p  = (mm != 0.f) ? __expf(mm - lv[c]) : 0.f;
                        G[r][j][c] = -invbuf[j*4 + c] * p;
                    }
                }
            }
            // dS = G @ Hw^T, bf16 into dsbuf (swizzled: t' = t ^ ((m&7)<<3))
            #pragma unroll
            for (int h = 0; h < NH; h++){
                f32x4 w0 = *(const f32x4*)&hw[h][0];
                f32x4 w1 = *(const f32x4*)&hw[h][4];
                f32x4 w2 = *(const f32x4*)&hw[h][8];
                #pragma unroll
                for (int r = 0; r < 4; r++){
                    f32x4 pr = G[r][0]*w0 + G[r][1]*w1 + G[r][2]*w2;
                    const float d = pr[0] + pr[1] + pr[2] + pr[3];
                    const int m = rsub*16 + quad*4 + r;
                    dsbuf[h][m][tA ^ ((m & 7) << 3)] = f2bf(d);
                }
            }
        }
        __syncthreads();

        // ---- phase B: dRow[m][z] += sum_kk dS[m][kk] * colmat[kk][z] ----
        #pragma unroll
        for (int hh = 0; hh < 3; hh++){
            const int h = csub + hh*4;
            #pragma unroll
            for (int ks = 0; ks < 2; ks++){
                const int mA = rsub*16 + col;
                bf16x8 a = *(const bf16x8*)&dsbuf[h][mA][(ks*32 + quad*8) ^ ((col & 7) << 3)];
                #pragma unroll
                for (int zt = 0; zt < 4; zt++){
                    const int ch = (h*HD + zt*16 + col) ^ (quad << 3);  // gather swizzle
                    bf16x8 b;
                    #pragma unroll
                    for (int jj = 0; jj < 8; jj++)
                        b[jj] = (short)colbuf[ks*32 + quad*8 + jj][ch];
                    accB[hh][zt] = __builtin_amdgcn_mfma_f32_16x16x32_bf16(a, b, accB[hh][zt], 0, 0, 0);
                }
            }
        }
    }
    float* outp = out_part + (size_t)blockIdx.y * N_TOK * CDIM;
    #pragma unroll
    for (int hh = 0; hh < 3; hh++){
        const int h = csub + hh*4;
        #pragma unroll
        for (int zt = 0; zt < 4; zt++)
            #pragma unroll
            for (int r = 0; r < 4; r++)
                outp[(size_t)(rbase + quad*4 + r) * CDIM + h*HD + zt*16 + col] = accB[hh][zt][r];
    }
}

// ---------------------------------------------------------------------------
// final: dg[n][d] = sum_c beta[c/64]*dQb[n][c]*Wq[c][d] + dKh[n][c]*Wk[c][d]
// ---------------------------------------------------------------------------
__global__ __launch_bounds__(256) void final_dg_kernel(
    const float* __restrict__ dQbp, const float* __restrict__ dKhp,
    const float* __restrict__ Wq, const float* __restrict__ Wk,
    const float* __restrict__ betas, float* __restrict__ dg, int nseg)
{
    __shared__ float at[16][68];
    __shared__ float bt[16][68];
    const int n0 = blockIdx.x * 64, d0 = blockIdx.y * 64;
    const int t  = threadIdx.x;
    const int tx = t & 15, ty = t >> 4;
    const int lr = t >> 2, lk = (t & 3) * 4;
    float acc[4][4] = {};
    for (int src = 0; src < 2; src++){
        const float* P = src ? dKhp : dQbp;
        const float* W = src ? Wk  : Wq;
        for (int c0 = 0; c0 < CDIM; c0 += 16){
            __syncthreads();
            f32x4 a = {0.f,0.f,0.f,0.f};
            for (int s = 0; s < nseg; s++)
                a += *(const f32x4*)&P[((size_t)s * N_TOK + n0 + lr) * CDIM + c0 + lk];
            if (src == 0){
                const float bs = betas[(c0 + lk) >> 6];
                a *= bs;
            }
            at[lk+0][lr] = a[0]; at[lk+1][lr] = a[1]; at[lk+2][lr] = a[2]; at[lk+3][lr] = a[3];
            {
                const int kk = t >> 4, dd = (t & 15) * 4;
                f32x4 wv = *(const f32x4*)&W[(size_t)(c0 + kk) * DIM_IN + d0 + dd];
                bt[kk][dd+0] = wv[0]; bt[kk][dd+1] = wv[1]; bt[kk][dd+2] = wv[2]; bt[kk][dd+3] = wv[3];
            }
            __syncthreads();
            #pragma unroll
            for (int kk = 0; kk < 16; kk++){
                f32x4 av = *(const f32x4*)&at[kk][ty*4];
                f32x4 bv = *(const f32x4*)&bt[kk][tx*4];
                #pragma unroll
                for (int i = 0; i < 4; i++)
                    #pragma unroll
                    for (int j = 0; j < 4; j++)
                        acc[i][j] += av[i] * bv[j];
            }
        }
    }
    #pragma unroll
    for (int i = 0; i < 4; i++)
        #pragma unroll
        for (int j = 0; j < 4; j++)
            dg[(size_t)(n0 + ty*4 + i) * DIM_IN + d0 + tx*4 + j] = acc[i][j];
}

// ---------------------------------------------------------------------------
extern "C" void kernel_launch(void* const* d_in, const int* in_sizes, int n_in,
                              void* d_out, int out_size, void* d_ws, size_t ws_size,
                              hipStream_t stream)
{
    const float* g     = (const float*)d_in[0];
    const float* adj   = (const float*)d_in[1];
    const float* Wk    = (const float*)d_in[2];
    const float* Wq    = (const float*)d_in[3];
    const float* Hw    = (const float*)d_in[4];
    const float* Bk    = (const float*)d_in[5];
    const float* Bq    = (const float*)d_in[6];
    const float* betas = (const float*)d_in[7];
    float* out = (float*)d_out;

    char* ws = (char*)d_ws;
    const size_t szQb   = (size_t)N_TOK * CDIM * sizeof(unsigned short); // 6291456
    const size_t szL    = (size_t)N_TOK * NH * sizeof(float);            // 196608
    const size_t szPart = (size_t)N_TOK * CDIM * sizeof(float);          // 12582912

    unsigned short* Qb = (unsigned short*)(ws);
    unsigned short* Kh = (unsigned short*)(ws + szQb);
    float* l_ws   = (float*)(ws + 2*szQb);
    float* lse_ws = (float*)(ws + 2*szQb + szL);
    char*  parts  = ws + 2*szQb + 2*szL;
    const size_t base = 2*szQb + 2*szL;

    int KS = 1;
    if      (ws_size >= base + 8*szPart) KS = 4;
    else if (ws_size >= base + 4*szPart) KS = 2;
    float* dQbp = (float*)parts;
    float* dKhp = (float*)(parts + (size_t)KS * szPart);

    hipMemsetAsync(l_ws, 0, szL, stream);
    hipMemsetAsync(d_out, 0, sizeof(float), stream);

    proj_kernel<<<dim3(64, 12), 256, 0, stream>>>(g, Wq, Bq, betas, Qb);
    proj_kernel<<<dim3(64, 12), 256, 0, stream>>>(g, Wk, Bk, nullptr, Kh);
    fwd_kernel<<<dim3(64, 8), 256, 0, stream>>>(Qb, Kh, adj, Hw, l_ws, N_TOK / 8);
    lse_energy_kernel<<<dim3(192), 256, 0, stream>>>(l_ws, lse_ws, betas, out);
    bwd_kernel<0><<<dim3(128, KS), 512, 0, stream>>>(Qb, Kh, adj, Hw, lse_ws, betas,
                                                     dQbp, N_TOK / KS);
    bwd_kernel<1><<<dim3(128, KS), 512, 0, stream>>>(Kh, Qb, adj, Hw, lse_ws, betas,
                                                     dKhp, N_TOK / KS);
    final_dg_kernel<<<dim3(64, 8), 256, 0, stream>>>(dQbp, dKhp, Wq, Wk, betas,
                                                     out + 1, KS);
}

// Round 5
// 1625.423 us; speedup vs baseline: 2.0111x; 1.1023x over previous
//
#include <hip/hip_runtime.h>
#include <stdint.h>

#define N_TOK 4096
#define DIM_IN 512
#define NH 12
#define HD 64
#define CDIM 768   // NH*HD

using f32x4  = __attribute__((ext_vector_type(4))) float;
using f32x16 = __attribute__((ext_vector_type(16))) float;
using bf16x8 = __attribute__((ext_vector_type(8))) short;

static __device__ __forceinline__ unsigned short f2bf(float f){
    union { float f; unsigned int u; } v; v.f = f;
    unsigned int r = v.u + 0x7fffu + ((v.u >> 16) & 1u);
    return (unsigned short)(r >> 16);
}

// ---------------------------------------------------------------------------
// proj: out[n][c] = (sum_d g[n][d]*W[c][d] + B[c]) * (scale ? scale[c/64] : 1)
// stored as bf16.  64x64 tile, BK=16, 256 threads, 4x4 micro.
// ---------------------------------------------------------------------------
__global__ __launch_bounds__(256) void proj_kernel(
    const float* __restrict__ g, const float* __restrict__ W,
    const float* __restrict__ B, const float* __restrict__ scale,
    unsigned short* __restrict__ out)
{
    __shared__ float at[16][68];
    __shared__ float bt[16][68];
    const int n0 = blockIdx.x * 64, c0 = blockIdx.y * 64;
    const int t  = threadIdx.x;
    const int tx = t & 15, ty = t >> 4;
    const int lr = t >> 2, lk = (t & 3) * 4;
    float acc[4][4] = {};
    for (int d0 = 0; d0 < DIM_IN; d0 += 16){
        __syncthreads();
        f32x4 gv = *(const f32x4*)&g[(size_t)(n0 + lr) * DIM_IN + d0 + lk];
        at[lk+0][lr] = gv[0]; at[lk+1][lr] = gv[1]; at[lk+2][lr] = gv[2]; at[lk+3][lr] = gv[3];
        f32x4 wv = *(const f32x4*)&W[(size_t)(c0 + lr) * DIM_IN + d0 + lk];
        bt[lk+0][lr] = wv[0]; bt[lk+1][lr] = wv[1]; bt[lk+2][lr] = wv[2]; bt[lk+3][lr] = wv[3];
        __syncthreads();
        #pragma unroll
        for (int kk = 0; kk < 16; kk++){
            f32x4 av = *(const f32x4*)&at[kk][ty*4];
            f32x4 bv = *(const f32x4*)&bt[kk][tx*4];
            #pragma unroll
            for (int i = 0; i < 4; i++)
                #pragma unroll
                for (int j = 0; j < 4; j++)
                    acc[i][j] += av[i] * bv[j];
        }
    }
    #pragma unroll
    for (int i = 0; i < 4; i++){
        const int n = n0 + ty*4 + i;
        #pragma unroll
        for (int j = 0; j < 4; j++){
            const int c = c0 + tx*4 + j;
            float v = acc[i][j] + B[c];
            if (scale) v *= scale[c >> 6];
            out[(size_t)n * CDIM + c] = f2bf(v);
        }
    }
}

// ---------------------------------------------------------------------------
// forward: per 16x16 (q,k) MFMA tile, 12 head scores -> Hw mix -> adj mask ->
// accumulate sum(exp) per (q-row, h').  atomicAdd partials into l_ws.
// ---------------------------------------------------------------------------
#define TKF 32
#define KBS 776   // ushort stride: 1552 B (16B aligned, 2-way-bank only)

__global__ __launch_bounds__(256, 2) void fwd_kernel(
    const unsigned short* __restrict__ Qb, const unsigned short* __restrict__ Kh,
    const float* __restrict__ adj, const float* __restrict__ HwG,
    float* __restrict__ l_ws, int seg_len)
{
    __shared__ unsigned short kbuf[TKF][KBS];
    __shared__ float hw[NH][12];
    const int t = threadIdx.x;
    if (t < NH * 12) hw[t / 12][t % 12] = HwG[t];
    const int lane = t & 63, wave = t >> 6;
    const int quad = lane >> 4, col = lane & 15;
    const int qt0 = blockIdx.x * 64 + wave * 16;
    const int kstart = blockIdx.y * seg_len;

    bf16x8 af[NH][2];
    {
        const int arow = qt0 + col;
        #pragma unroll
        for (int h = 0; h < NH; h++)
            #pragma unroll
            for (int kk = 0; kk < 2; kk++)
                af[h][kk] = *(const bf16x8*)&Qb[(size_t)arow * CDIM + h*HD + kk*32 + quad*8];
    }
    f32x4 l4[4][3];
    #pragma unroll
    for (int r = 0; r < 4; r++)
        #pragma unroll
        for (int j = 0; j < 3; j++)
            l4[r][j] = (f32x4){0.f,0.f,0.f,0.f};

    for (int kc = kstart; kc < kstart + seg_len; kc += TKF){
        __syncthreads();
        #pragma unroll
        for (int i = 0; i < 12; i++){
            const int idx = t + 256 * i;
            const int row = idx / 96, cc = (idx % 96) * 8;
            *(bf16x8*)&kbuf[row][cc] = *(const bf16x8*)&Kh[(size_t)(kc + row) * CDIM + cc];
        }
        __syncthreads();
        #pragma unroll
        for (int sub = 0; sub < 2; sub++){
            const int k0 = kc + sub * 16;
            f32x4 tv[4][3];
            #pragma unroll
            for (int r = 0; r < 4; r++)
                #pragma unroll
                for (int j = 0; j < 3; j++)
                    tv[r][j] = (f32x4){0.f,0.f,0.f,0.f};
            #pragma unroll
            for (int h = 0; h < NH; h++){
                bf16x8 b0 = *(const bf16x8*)&kbuf[sub*16 + col][h*HD + quad*8];
                bf16x8 b1 = *(const bf16x8*)&kbuf[sub*16 + col][h*HD + 32 + quad*8];
                f32x4 s = {0.f,0.f,0.f,0.f};
                s = __builtin_amdgcn_mfma_f32_16x16x32_bf16(af[h][0], b0, s, 0, 0, 0);
                s = __builtin_amdgcn_mfma_f32_16x16x32_bf16(af[h][1], b1, s, 0, 0, 0);
                f32x4 w0 = *(const f32x4*)&hw[h][0];
                f32x4 w1 = *(const f32x4*)&hw[h][4];
                f32x4 w2 = *(const f32x4*)&hw[h][8];
                #pragma unroll
                for (int r = 0; r < 4; r++){
                    tv[r][0] += s[r] * w0;
                    tv[r][1] += s[r] * w1;
                    tv[r][2] += s[r] * w2;
                }
            }
            #pragma unroll
            for (int r = 0; r < 4; r++){
                const float adjv = adj[(size_t)(qt0 + quad*4 + r) * N_TOK + k0 + col];
                #pragma unroll
                for (int j = 0; j < 3; j++){
                    #pragma unroll
                    for (int c = 0; c < 4; c++){
                        const float mm = tv[r][j][c] * adjv;   // matches T*adj
                        if (mm != 0.f) l4[r][j][c] += __expf(mm);
                    }
                }
            }
        }
    }
    #pragma unroll
    for (int r = 0; r < 4; r++)
        #pragma unroll
        for (int j = 0; j < 3; j++)
            #pragma unroll
            for (int c = 0; c < 4; c++){
                float v = l4[r][j][c];
                v += __shfl_xor(v, 1, 16);
                v += __shfl_xor(v, 2, 16);
                v += __shfl_xor(v, 4, 16);
                v += __shfl_xor(v, 8, 16);
                if (col == j*4 + c)
                    atomicAdd(&l_ws[(size_t)(qt0 + quad*4 + r) * NH + (j*4 + c)], v);
            }
}

// ---------------------------------------------------------------------------
// lse + energy
// ---------------------------------------------------------------------------
__global__ __launch_bounds__(256) void lse_energy_kernel(
    const float* __restrict__ l_ws, float* __restrict__ lse_ws,
    const float* __restrict__ betas, float* __restrict__ energy)
{
    const int t = threadIdx.x;
    const int i = blockIdx.x * 256 + t;
    const float l = l_ws[i];
    float lse, ep;
    if (l > 0.f){ lse = logf(l); ep = -(1.f / betas[i % NH]) * lse; }
    else        { lse = -1e30f; ep = 0.f; }
    lse_ws[i] = lse;
    __shared__ float red[256];
    red[t] = ep;
    __syncthreads();
    for (int s = 128; s > 0; s >>= 1){
        if (t < s) red[t] += red[t + s];
        __syncthreads();
    }
    if (t == 0) atomicAdd(energy, red[0]);
}

// ---------------------------------------------------------------------------
// backward: 512 threads / 8 waves per block, 32-row tile, 64-col chunks.
// r4 established: 2 waves/EU -> 256 unified regs, demand ~170, no spill,
// FETCH ~197MB (real).  Remaining stalls: serial staging between barriers,
// and phase-B's 192 ds_read_u16 transpose gather per wave per chunk.
// r5 changes:
//  (1) T14 async-STAGE: chunk t+1's colmat/adj/lse loaded into regs (pcol/
//      padj/plse, ~56 VGPRs) at END of phase A of chunk t; ds_write at top of
//      next iteration.  HBM/L2 latency hides under phase B.
//  (2) phase B uses mfma_f32_32x32x16_bf16: wave w owns (h,cg) groups
//      {w,w+8,w+16} (h=g>>1, cg=g&1), all 32 rows.  A = dsbuf[h][lane&31]
//      b128 contiguous (swizzle-compatible); B = 96 u16 gathers (half of
//      before), ch constant across jj -> base + offset: immediates.
//      D layout: col=lane&31, row=(reg&3)+8*(reg>>2)+4*(lane>>5).
// Peak regs ~210 <= 256.  LDS unchanged (<=161KB, 1 block/CU).
// ---------------------------------------------------------------------------
#define CBS 776   // colbuf ushort stride

template<int MODE>
__global__ __attribute__((amdgpu_flat_work_group_size(512, 512), amdgpu_waves_per_eu(2, 2)))
void bwd_kernel(
    const unsigned short* __restrict__ rowmat, const unsigned short* __restrict__ colmat,
    const float* __restrict__ adj, const float* __restrict__ HwG,
    const float* __restrict__ lse_ws, const float* __restrict__ betas,
    float* __restrict__ out_part, int seg_len)
{
    __shared__ unsigned short colbuf[64][CBS];     // 99328 B
    __shared__ unsigned short dsbuf[NH][32][64];   // 49152 B
    __shared__ float adjbuf[32][68];               //  8704 B
    __shared__ float lsebuf[64 * NH];              //  3072 B (mode 1 only)
    __shared__ float rowlse[32 * NH];              //  1536 B (mode 0 only)
    __shared__ float invbuf[NH];                   //    48 B
    __shared__ float hw[NH][12];                   //   576 B
    const int t = threadIdx.x;
    if (t < NH * 12) hw[t / 12][t % 12] = HwG[t];
    if (t < NH) invbuf[t] = 1.f / betas[t];
    const int lane = t & 63, wave = t >> 6;
    const int quad = lane >> 4, col = lane & 15;
    const int rsub = wave >> 2, csub = wave & 3;
    const int n0 = csub * 16;
    const int rt0 = blockIdx.x * 32;
    const int rbase = rt0 + rsub * 16;       // this wave's 16 rows (phase A)
    const int cstart = blockIdx.y * seg_len;

    if (MODE == 0 && t < 96)
        *(f32x4*)&rowlse[t*4] = *(const f32x4*)&lse_ws[(size_t)rt0 * NH + t*4];

    // A-fragment source row for this lane (16 B aligned vector loads)
    const unsigned short* rowp = &rowmat[(size_t)(rbase + col) * CDIM + quad*8];

    // staging-prefetch decomposition (indices fixed per thread)
    const int strow = t / 96 * 0;  // placeholder to keep style; real indices below
    (void)strow;
    const int adj_m  = t >> 4, adj_nc = (t & 15) * 4;   // mode 0
    const int adj_qr = t >> 3, adj_kc = (t & 7) * 4;    // mode 1

    // ---- initial prefetch (chunk 0) ----
    bf16x8 pcol[12];
    f32x4  padj;
    f32x4  plse = {0.f,0.f,0.f,0.f};
    {
        const int cb = cstart;
        #pragma unroll
        for (int i = 0; i < 12; i++){
            const int idx = t + 512 * i;
            const int row = idx / 96, cc = (idx % 96) * 8;
            pcol[i] = *(const bf16x8*)&colmat[(size_t)(cb + row) * CDIM + cc];
        }
        if (MODE == 0) padj = *(const f32x4*)&adj[(size_t)(rt0 + adj_m) * N_TOK + cb + adj_nc];
        else           padj = *(const f32x4*)&adj[(size_t)(cb + adj_qr) * N_TOK + rt0 + adj_kc];
        if (MODE == 1 && t < 192)
            plse = *(const f32x4*)&lse_ws[(size_t)cb * NH + t*4];
    }

    f32x16 accB32[3];
    #pragma unroll
    for (int gg = 0; gg < 3; gg++)
        #pragma unroll
        for (int q = 0; q < 16; q++) accB32[gg][q] = 0.f;

    for (int cb = cstart; cb < cstart + seg_len; cb += 64){
        __syncthreads();
        // ---- write prefetched chunk into LDS ----
        #pragma unroll
        for (int i = 0; i < 12; i++){
            const int idx = t + 512 * i;
            const int row = idx / 96, cc = (idx % 96) * 8;
            // swizzled store: logical channel c lives at c ^ ((row>>3 & 3)<<3)
            *(bf16x8*)&colbuf[row][cc ^ (((row >> 3) & 3) << 3)] = pcol[i];
        }
        if (MODE == 0){
            adjbuf[adj_m][adj_nc+0] = padj[0]; adjbuf[adj_m][adj_nc+1] = padj[1];
            adjbuf[adj_m][adj_nc+2] = padj[2]; adjbuf[adj_m][adj_nc+3] = padj[3];
        } else {
            adjbuf[adj_kc+0][adj_qr] = padj[0]; adjbuf[adj_kc+1][adj_qr] = padj[1];
            adjbuf[adj_kc+2][adj_qr] = padj[2]; adjbuf[adj_kc+3][adj_qr] = padj[3];
        }
        if (MODE == 1 && t < 192)
            *(f32x4*)&lsebuf[t*4] = plse;
        __syncthreads();

        // launder the A-row pointer so the per-h loads below cannot be
        // hoisted out of the cb loop (would recreate a 96-reg af array)
        const unsigned short* rp = rowp;
        asm volatile("" : "+v"(rp));

        // ---- phase A: this wave's 16 rows x 16 cols (csub subtile) ----
        {
            const int tA = n0 + col;
            const int swzA = ((tA >> 3) & 3) << 3;
            f32x4 G[4][3];
            #pragma unroll
            for (int r = 0; r < 4; r++)
                #pragma unroll
                for (int j = 0; j < 3; j++)
                    G[r][j] = (f32x4){0.f,0.f,0.f,0.f};
            #pragma unroll
            for (int h = 0; h < NH; h++){
                bf16x8 a0 = *(const bf16x8*)&rp[h*HD];
                bf16x8 a1 = *(const bf16x8*)&rp[h*HD + 32];
                bf16x8 b0 = *(const bf16x8*)&colbuf[tA][(h*HD + quad*8) ^ swzA];
                bf16x8 b1 = *(const bf16x8*)&colbuf[tA][(h*HD + 32 + quad*8) ^ swzA];
                f32x4 s = {0.f,0.f,0.f,0.f};
                s = __builtin_amdgcn_mfma_f32_16x16x32_bf16(a0, b0, s, 0, 0, 0);
                s = __builtin_amdgcn_mfma_f32_16x16x32_bf16(a1, b1, s, 0, 0, 0);
                f32x4 w0 = *(const f32x4*)&hw[h][0];
                f32x4 w1 = *(const f32x4*)&hw[h][4];
                f32x4 w2 = *(const f32x4*)&hw[h][8];
                #pragma unroll
                for (int r = 0; r < 4; r++){
                    G[r][0] += s[r] * w0;
                    G[r][1] += s[r] * w1;
                    G[r][2] += s[r] * w2;
                }
            }
            // convert t-values -> gradient G = -(1/b')*P   (lse + 1/beta from LDS)
            #pragma unroll
            for (int r = 0; r < 4; r++){
                const float adjv = adjbuf[rsub*16 + quad*4 + r][tA];
                #pragma unroll
                for (int j = 0; j < 3; j++){
                    f32x4 lv;
                    if (MODE == 0) lv = *(const f32x4*)&rowlse[(rsub*16 + quad*4 + r) * NH + j*4];
                    else           lv = *(const f32x4*)&lsebuf[tA * NH + j*4];
                    #pragma unroll
                    for (int c = 0; c < 4; c++){
                        const float mm = G[r][j][c] * adjv;
                        const float p  = (mm != 0.f) ? __expf(mm - lv[c]) : 0.f;
                        G[r][j][c] = -invbuf[j*4 + c] * p;
                    }
                }
            }
            // dS = G @ Hw^T, bf16 into dsbuf (swizzled: kk' = kk ^ ((m&7)<<3))
            #pragma unroll
            for (int h = 0; h < NH; h++){
                f32x4 w0 = *(const f32x4*)&hw[h][0];
                f32x4 w1 = *(const f32x4*)&hw[h][4];
                f32x4 w2 = *(const f32x4*)&hw[h][8];
                #pragma unroll
                for (int r = 0; r < 4; r++){
                    f32x4 pr = G[r][0]*w0 + G[r][1]*w1 + G[r][2]*w2;
                    const float d = pr[0] + pr[1] + pr[2] + pr[3];
                    const int m = rsub*16 + quad*4 + r;
                    dsbuf[h][m][tA ^ ((m & 7) << 3)] = f2bf(d);
                }
            }
        }

        // ---- issue prefetch of chunk t+1 (hides under phase B) ----
        {
            const int nxt = cb + 64;
            const int cbn = (nxt < cstart + seg_len) ? nxt : cstart;  // clamp (discarded)
            #pragma unroll
            for (int i = 0; i < 12; i++){
                const int idx = t + 512 * i;
                const int row = idx / 96, cc = (idx % 96) * 8;
                pcol[i] = *(const bf16x8*)&colmat[(size_t)(cbn + row) * CDIM + cc];
            }
            if (MODE == 0) padj = *(const f32x4*)&adj[(size_t)(rt0 + adj_m) * N_TOK + cbn + adj_nc];
            else           padj = *(const f32x4*)&adj[(size_t)(cbn + adj_qr) * N_TOK + rt0 + adj_kc];
            if (MODE == 1 && t < 192)
                plse = *(const f32x4*)&lse_ws[(size_t)cbn * NH + t*4];
        }
        __syncthreads();

        // ---- phase B (32x32x16): dRow[m][z] += sum_kk dS[m][kk]*colmat[kk][z]
        // wave owns groups g = wave, wave+8, wave+16:  h = g>>1, cg = g&1
        {
            const int mB = lane & 31;       // A row / D col-lane
            const int halfB = lane >> 5;    // k half
            #pragma unroll
            for (int gg = 0; gg < 3; gg++){
                const int gidx = wave + gg*8;
                const int h = gidx >> 1, cg = gidx & 1;
                const int chL = h*HD + cg*32 + mB;     // logical chan for B
                f32x16 acc = accB32[gg];
                #pragma unroll
                for (int k0 = 0; k0 < 64; k0 += 16){
                    const int kbase = k0 + halfB*8;
                    // A: dS[mB][kbase .. +8]  (swizzle-compatible contiguous)
                    bf16x8 a = *(const bf16x8*)&dsbuf[h][mB][kbase ^ ((mB & 7) << 3)];
                    // B: colmat[kbase+jj][chL], jj=0..7 ; swizzle const over jj
                    const int sw = ((kbase >> 3) & 3) << 3;
                    const unsigned short* bp = &colbuf[kbase][chL ^ sw];
                    bf16x8 b;
                    #pragma unroll
                    for (int jj = 0; jj < 8; jj++)
                        b[jj] = (short)bp[jj * CBS];
                    acc = __builtin_amdgcn_mfma_f32_32x32x16_bf16(a, b, acc, 0, 0, 0);
                }
                accB32[gg] = acc;
            }
        }
    }
    // ---- write dRow partials (32x32 D layout) ----
    float* outp = out_part + (size_t)blockIdx.y * N_TOK * CDIM;
    #pragma unroll
    for (int gg = 0; gg < 3; gg++){
        const int gidx = wave + gg*8;
        const int h = gidx >> 1, cg = gidx & 1;
        #pragma unroll
        for (int q = 0; q < 16; q++){
            const int i = (q & 3) + 8*(q >> 2) + 4*(lane >> 5);
            outp[(size_t)(rt0 + i) * CDIM + h*HD + cg*32 + (lane & 31)] = accB32[gg][q];
        }
    }
}

// ---------------------------------------------------------------------------
// final: dg[n][d] = sum_c beta[c/64]*dQb[n][c]*Wq[c][d] + dKh[n][c]*Wk[c][d]
// ---------------------------------------------------------------------------
__global__ __launch_bounds__(256) void final_dg_kernel(
    const float* __restrict__ dQbp, const float* __restrict__ dKhp,
    const float* __restrict__ Wq, const float* __restrict__ Wk,
    const float* __restrict__ betas, float* __restrict__ dg, int nseg)
{
    __shared__ float at[16][68];
    __shared__ float bt[16][68];
    const int n0 = blockIdx.x * 64, d0 = blockIdx.y * 64;
    const int t  = threadIdx.x;
    const int tx = t & 15, ty = t >> 4;
    const int lr = t >> 2, lk = (t & 3) * 4;
    float acc[4][4] = {};
    for (int src = 0; src < 2; src++){
        const float* P = src ? dKhp : dQbp;
        const float* W = src ? Wk  : Wq;
        for (int c0 = 0; c0 < CDIM; c0 += 16){
            __syncthreads();
            f32x4 a = {0.f,0.f,0.f,0.f};
            for (int s = 0; s < nseg; s++)
                a += *(const f32x4*)&P[((size_t)s * N_TOK + n0 + lr) * CDIM + c0 + lk];
            if (src == 0){
                const float bs = betas[(c0 + lk) >> 6];
                a *= bs;
            }
            at[lk+0][lr] = a[0]; at[lk+1][lr] = a[1]; at[lk+2][lr] = a[2]; at[lk+3][lr] = a[3];
            {
                const int kk = t >> 4, dd = (t & 15) * 4;
                f32x4 wv = *(const f32x4*)&W[(size_t)(c0 + kk) * DIM_IN + d0 + dd];
                bt[kk][dd+0] = wv[0]; bt[kk][dd+1] = wv[1]; bt[kk][dd+2] = wv[2]; bt[kk][dd+3] = wv[3];
            }
            __syncthreads();
            #pragma unroll
            for (int kk = 0; kk < 16; kk++){
                f32x4 av = *(const f32x4*)&at[kk][ty*4];
                f32x4 bv = *(const f32x4*)&bt[kk][tx*4];
                #pragma unroll
                for (int i = 0; i < 4; i++)
                    #pragma unroll
                    for (int j = 0; j < 4; j++)
                        acc[i][j] += av[i] * bv[j];
            }
        }
    }
    #pragma unroll
    for (int i = 0; i < 4; i++)
        #pragma unroll
        for (int j = 0; j < 4; j++)
            dg[(size_t)(n0 + ty*4 + i) * DIM_IN + d0 + tx*4 + j] = acc[i][j];
}

// ---------------------------------------------------------------------------
extern "C" void kernel_launch(void* const* d_in, const int* in_sizes, int n_in,
                              void* d_out, int out_size, void* d_ws, size_t ws_size,
                              hipStream_t stream)
{
    const float* g     = (const float*)d_in[0];
    const float* adj   = (const float*)d_in[1];
    const float* Wk    = (const float*)d_in[2];
    const float* Wq    = (const float*)d_in[3];
    const float* Hw    = (const float*)d_in[4];
    const float* Bk    = (const float*)d_in[5];
    const float* Bq    = (const float*)d_in[6];
    const float* betas = (const float*)d_in[7];
    float* out = (float*)d_out;

    char* ws = (char*)d_ws;
    const size_t szQb   = (size_t)N_TOK * CDIM * sizeof(unsigned short); // 6291456
    const size_t szL    = (size_t)N_TOK * NH * sizeof(float);            // 196608
    const size_t szPart = (size_t)N_TOK * CDIM * sizeof(float);          // 12582912

    unsigned short* Qb = (unsigned short*)(ws);
    unsigned short* Kh = (unsigned short*)(ws + szQb);
    float* l_ws   = (float*)(ws + 2*szQb);
    float* lse_ws = (float*)(ws + 2*szQb + szL);
    char*  parts  = ws + 2*szQb + 2*szL;
    const size_t base = 2*szQb + 2*szL;

    int KS = 1;
    if      (ws_size >= base + 8*szPart) KS = 4;
    else if (ws_size >= base + 4*szPart) KS = 2;
    float* dQbp = (float*)parts;
    float* dKhp = (float*)(parts + (size_t)KS * szPart);

    hipMemsetAsync(l_ws, 0, szL, stream);
    hipMemsetAsync(d_out, 0, sizeof(float), stream);

    proj_kernel<<<dim3(64, 12), 256, 0, stream>>>(g, Wq, Bq, betas, Qb);
    proj_kernel<<<dim3(64, 12), 256, 0, stream>>>(g, Wk, Bk, nullptr, Kh);
    fwd_kernel<<<dim3(64, 8), 256, 0, stream>>>(Qb, Kh, adj, Hw, l_ws, N_TOK / 8);
    lse_energy_kernel<<<dim3(192), 256, 0, stream>>>(l_ws, lse_ws, betas, out);
    bwd_kernel<0><<<dim3(128, KS), 512, 0, stream>>>(Qb, Kh, adj, Hw, lse_ws, betas,
                                                     dQbp, N_TOK / KS);
    bwd_kernel<1><<<dim3(128, KS), 512, 0, stream>>>(Kh, Qb, adj, Hw, lse_ws, betas,
                                                     dKhp, N_TOK / KS);
    final_dg_kernel<<<dim3(64, 8), 256, 0, stream>>>(dQbp, dKhp, Wq, Wk, betas,
                                                     out + 1, KS);
}